// Round 16
// baseline (190.612 us; speedup 1.0000x reference)
//
#include <hip/hip_runtime.h>
#include <hip/hip_bf16.h>

typedef unsigned short u16;
typedef __bf16 bf16x8 __attribute__((ext_vector_type(8)));
typedef float f32x4 __attribute__((ext_vector_type(4)));
typedef unsigned short ushort8 __attribute__((ext_vector_type(8)));

#define AS1 __attribute__((address_space(1)))
#define AS3 __attribute__((address_space(3)))

__device__ inline u16 f2bf(float f) {
  union { float f; unsigned int u; } c; c.f = f;
  unsigned int u = c.u;
  return (u16)((u + 0x7fffu + ((u >> 16) & 1u)) >> 16);
}
__device__ inline float bf2f(u16 v) {
  union { unsigned int u; float f; } c; c.u = ((unsigned int)v) << 16;
  return c.f;
}

// ---------------- fused x conversion + transpose ----------------
__global__ __launch_bounds__(256) void cvt_x_dual(const float* __restrict__ x,
                                                  u16* __restrict__ xbf,
                                                  u16* __restrict__ xT) {
  __shared__ u16 tile[64][68];
  const int t = threadIdx.x;
  const long e0 = (long)blockIdx.x * 64;     // feature tile
  const long l0 = (long)blockIdx.y * 64;     // token tile within batch
  const long b  = blockIdx.z;
  const int tr = t >> 4, tc = t & 15;
#pragma unroll
  for (int i = 0; i < 4; ++i) {
    const int r = tr + i * 16;
    const long gl = b * 4096 + l0 + r;
    float4 v = *reinterpret_cast<const float4*>(x + gl * 1024 + e0 + tc * 4);
    ushort4 o;
    o.x = f2bf(v.x); o.y = f2bf(v.y); o.z = f2bf(v.z); o.w = f2bf(v.w);
    *reinterpret_cast<ushort4*>(xbf + gl * 1024 + e0 + tc * 4) = o;
    *reinterpret_cast<ushort4*>(&tile[r][tc * 4]) = o;
  }
  __syncthreads();
#pragma unroll
  for (int i = 0; i < 4; ++i) {
    const int c = tr + i * 16;
    ushort4 o;
    o.x = tile[tc * 4 + 0][c]; o.y = tile[tc * 4 + 1][c];
    o.z = tile[tc * 4 + 2][c]; o.w = tile[tc * 4 + 3][c];
    *reinterpret_cast<ushort4*>(xT + b * (1024L * 4096) + (e0 + c) * 4096 + l0 + tc * 4) = o;
  }
}

// ---------------- fused conversion of the 4 weight matrices ----------------
__global__ __launch_bounds__(256) void cvt_w4(const float* __restrict__ a, const float* __restrict__ b,
                                              const float* __restrict__ c, const float* __restrict__ d,
                                              u16* __restrict__ oa, u16* __restrict__ ob,
                                              u16* __restrict__ oc, u16* __restrict__ od) {
  int i = blockIdx.x * 256 + threadIdx.x;
  const int which = i >> 18;
  const int j = i & 262143;
  const float* src = which == 0 ? a : which == 1 ? b : which == 2 ? c : d;
  u16* dst = which == 0 ? oa : which == 1 ? ob : which == 2 ? oc : od;
  float4 v = reinterpret_cast<const float4*>(src)[j];
  ushort4 o;
  o.x = f2bf(v.x); o.y = f2bf(v.y); o.z = f2bf(v.z); o.w = f2bf(v.w);
  reinterpret_cast<ushort4*>(dst)[j] = o;
}

// ---------------- bf16 tiled transpose ----------------
__global__ __launch_bounds__(256) void transpose_bf16(
    const u16* __restrict__ src, long sLd, long sZ,
    u16* __restrict__ dst, long dLd, long dZ) {
  __shared__ u16 tile[64][68];
  const int t = threadIdx.x;
  const long r0 = (long)blockIdx.y * 64;
  const long c0 = (long)blockIdx.x * 64;
  const long z = blockIdx.z;
  const int tr = t >> 4, tc = t & 15;
#pragma unroll
  for (int i = 0; i < 4; ++i) {
    const int r = tr + i * 16;
    ushort4 v = *reinterpret_cast<const ushort4*>(src + z * sZ + (r0 + r) * sLd + c0 + tc * 4);
    *reinterpret_cast<ushort4*>(&tile[r][tc * 4]) = v;
  }
  __syncthreads();
#pragma unroll
  for (int i = 0; i < 4; ++i) {
    const int c = tr + i * 16;
    ushort4 o;
    o.x = tile[tc * 4 + 0][c]; o.y = tile[tc * 4 + 1][c];
    o.z = tile[tc * 4 + 2][c]; o.w = tile[tc * 4 + 3][c];
    *reinterpret_cast<ushort4*>(dst + z * dZ + (c0 + c) * dLd + r0 + tc * 4) = o;
  }
}

// ---- staging helpers via gload_lds (pre-swizzled source) ----
__device__ __forceinline__ void stage_half(const u16* __restrict__ g, long ld, int k0,
                                           u16* dst, int t) {
#pragma unroll
  for (int i = 0; i < 2; ++i) {
    const int c = i * 512 + t;
    const int r = c >> 3;
    const int s = c & 7;
    const int col = ((s ^ (r & 7)) << 3) + k0;
    __builtin_amdgcn_global_load_lds((const AS1 void*)(g + (long)r * ld + col),
                                     (AS3 void*)(dst + c * 8), 16, 0, 0);
  }
}

// 256-thread variant: N16 chunks per thread (rows = N16*256/8)
template<int N16>
__device__ __forceinline__ void stage_rows256(const u16* __restrict__ g, long ld, int k0,
                                              u16* dst, int t) {
#pragma unroll
  for (int i = 0; i < N16; ++i) {
    const int c = i * 256 + t;
    const int r = c >> 3;
    const int s = c & 7;
    const int col = ((s ^ (r & 7)) << 3) + k0;
    __builtin_amdgcn_global_load_lds((const AS1 void*)(g + (long)r * ld + col),
                                     (AS3 void*)(dst + c * 8), 16, 0, 0);
  }
}

__device__ __forceinline__ bf16x8 frag_ld(const u16* s, int row, int colb) {
  return *reinterpret_cast<const bf16x8*>(
      reinterpret_cast<const char*>(s) + row * 128 + (colb ^ ((row & 7) << 4)));
}

__device__ __forceinline__ void read_a(bf16x8 (&a)[4][2], const u16* half, int wrow, int llo, int lhi) {
#pragma unroll
  for (int fr = 0; fr < 4; ++fr)
#pragma unroll
    for (int kk = 0; kk < 2; ++kk)
      a[fr][kk] = frag_ld(half, wrow + fr * 16 + llo, (kk << 6) + (lhi << 4));
}
__device__ __forceinline__ void read_b(bf16x8 (&b)[2][2], const u16* half, int wcol, int llo, int lhi) {
#pragma unroll
  for (int fc = 0; fc < 2; ++fc)
#pragma unroll
    for (int kk = 0; kk < 2; ++kk)
      b[fc][kk] = frag_ld(half, wcol + fc * 16 + llo, (kk << 6) + (lhi << 4));
}
__device__ __forceinline__ void mfma_quad(f32x4 (&q)[4][2], bf16x8 (&af)[4][2], bf16x8 (&bf)[2][2]) {
  __builtin_amdgcn_s_setprio(1);
#pragma unroll
  for (int fr = 0; fr < 4; ++fr)
#pragma unroll
    for (int fc = 0; fc < 2; ++fc)
#pragma unroll
      for (int kk = 0; kk < 2; ++kk)
        q[fr][fc] = __builtin_amdgcn_mfma_f32_16x16x32_bf16(af[fr][kk], bf[fc][kk], q[fr][fc], 0, 0, 0);
  __builtin_amdgcn_s_setprio(0);
}

// ---- flattened bijective XCD swizzle (total % 8 == 0 at all call sites) ----
#define XCD_DECODE2(TM, TN)                                                  \
  const int nxy = gridDim.x * gridDim.y;                                     \
  int flat = blockIdx.x + gridDim.x * blockIdx.y + nxy * blockIdx.z;         \
  const int total = nxy * gridDim.z;                                         \
  const int qq = total >> 3;                                                 \
  flat = (flat & 7) * qq + (flat >> 3);                                      \
  const int z = flat / nxy;                                                  \
  const int wg = flat % nxy;                                                 \
  const long m0 = (long)(wg % gridDim.x) * (TM);                             \
  const long n0 = (long)(wg / gridDim.x) * (TN);

// ====== 256x256 NT GEMM — 8-phase / 2-K-tile template (T3+T4), BK=64 =========
// 8 waves (2x4), LDS 128 KiB = 2 buf x {A0,A1,B0,B1} halves of [128][64] bf16.
// Per iteration (tiles t0=2i in buf0, t1=2i+1 in buf1), 8 phases; each phase:
// {ds-reads (12/4/8/0), stage 1 half-tile, [lgkmcnt(8) if 12 reads],
//  [vmcnt(6) at ph4/ph8 ONLY], barrier, lgkmcnt(0)+sched_barrier, 16 MFMA,
//  barrier}. Stage slots: S1=A1(t1)->buf1, S2=A0(t0+2), S3=B0(t0+2),
// S4=B1(t0+2), S5=A1(t0+2) (all buf0), S6=A0(t1+2), S7=B0(t1+2), S8=B1(t1+2)
// (buf1). WAR: every slot staged >=1 barrier after its last read. RAW: ph4/ph8
// vmcnt(6) (keep last 3 stages) retires every slot before its first read
// (ledger verified incl. prologue 7-stage state and wrapped-dead tail).
// Requires NT even, >= 4.
#define PH_SYNC()    do { __builtin_amdgcn_s_barrier();                           \
                          asm volatile("s_waitcnt lgkmcnt(0)" ::: "memory");      \
                          __builtin_amdgcn_sched_barrier(0); } while (0)
#define PH_SYNC_VM() do { asm volatile("s_waitcnt vmcnt(6)" ::: "memory");        \
                          __builtin_amdgcn_s_barrier();                           \
                          asm volatile("s_waitcnt lgkmcnt(0)" ::: "memory");      \
                          __builtin_amdgcn_sched_barrier(0); } while (0)
#define PH_END()     do { asm volatile("" ::: "memory");                          \
                          __builtin_amdgcn_s_barrier();                           \
                          asm volatile("" ::: "memory"); } while (0)
#define LGKM_HINT()  asm volatile("s_waitcnt lgkmcnt(8)" ::: "memory")

template<bool OUT_F32>
__global__ __launch_bounds__(512, 2) void gemm_nt256(
    const u16* __restrict__ A, long lda, long sAz4, long sAz1,
    const u16* __restrict__ B, long ldb, long sBz4, long sBz1,
    void* __restrict__ Cv, long ldc, long sCz4, long sCz1,
    long cBatch, int cShift,
    int K, float scale)
{
  __shared__ u16 sm[2 * 32768] __attribute__((aligned(16)));  // 128 KiB

  const int t = threadIdx.x;
  XCD_DECODE2(256, 256);
  const long azoff = (long)(z >> 2) * sAz4 + (long)(z & 3) * sAz1;
  const long bzoff = (long)(z >> 2) * sBz4 + (long)(z & 3) * sBz1;
  const u16* Ab = A + azoff + m0 * lda;
  const u16* Bb = B + bzoff + n0 * ldb;

  const int wid = t >> 6, lane = t & 63;
  const int lhi = lane >> 4, llo = lane & 15;
  const int wm = wid >> 2, wn = wid & 3;
  const int war = wm * 64;            // wave row base within an A-half
  const int wbc = wn * 32;            // wave col base within a B-half

  u16* buf0 = sm;
  u16* buf1 = sm + 32768;
  f32x4 acc[2][2][4][2] = {};         // [ah][bh][fr][fc]
  const int NT = K >> 6;              // even, >= 4

  // prologue: tile0 fully + tile1's {A0,B0,B1}; leave those 3 stages in flight
  stage_half(Ab, lda, 0, buf0, t);                       // A0(0)
  stage_half(Bb, ldb, 0, buf0 + 16384, t);               // B0(0)
  stage_half(Bb + 128 * ldb, ldb, 0, buf0 + 24576, t);   // B1(0)
  stage_half(Ab + 128 * lda, lda, 0, buf0 + 8192, t);    // A1(0)
  stage_half(Ab, lda, 64, buf1, t);                      // A0(1)
  stage_half(Bb, ldb, 64, buf1 + 16384, t);              // B0(1)
  stage_half(Bb + 128 * ldb, ldb, 64, buf1 + 24576, t);  // B1(1)
  asm volatile("s_waitcnt vmcnt(6)" ::: "memory");       // tile0 resident
  __builtin_amdgcn_s_barrier();
  asm volatile("" ::: "memory");

  for (int it = 0; it < (NT >> 1); ++it) {
    const int k1b = (2 * it + 1) << 6;                   // t1 (never wraps)
    const int t2a = 2 * it + 2, t2b = 2 * it + 3;
    const int k2a = ((t2a < NT) ? t2a : t2a - NT) << 6;  // wrapped-dead at tail
    const int k2b = ((t2b < NT) ? t2b : t2b - NT) << 6;
    bf16x8 aLo[4][2], aHi[4][2], bLo[2][2], bHi[2][2];

    // ph1: reads aLo,bLo(buf0) [12]; S1 = A1(t1)->buf1; MFMA q00(t0)
    read_a(aLo, buf0, war, llo, lhi);
    read_b(bLo, buf0 + 16384, wbc, llo, lhi);
    stage_half(Ab + 128 * lda, lda, k1b, buf1 + 8192, t);
    LGKM_HINT();
    PH_SYNC();
    mfma_quad(acc[0][0], aLo, bLo);
    PH_END();

    // ph2: reads bHi(buf0) [4]; S2 = A0(t0+2)->buf0; MFMA q01(t0)
    read_b(bHi, buf0 + 24576, wbc, llo, lhi);
    stage_half(Ab, lda, k2a, buf0, t);
    PH_SYNC();
    mfma_quad(acc[0][1], aLo, bHi);
    PH_END();

    // ph3: reads aHi(buf0) [8]; S3 = B0(t0+2)->buf0; MFMA q11(t0)
    read_a(aHi, buf0 + 8192, war, llo, lhi);
    stage_half(Bb, ldb, k2a, buf0 + 16384, t);
    PH_SYNC();
    mfma_quad(acc[1][1], aHi, bHi);
    PH_END();

    // ph4: no reads; S4 = B1(t0+2)->buf0; vmcnt(6); MFMA q10(t0)
    stage_half(Bb + 128 * ldb, ldb, k2a, buf0 + 24576, t);
    PH_SYNC_VM();
    mfma_quad(acc[1][0], aHi, bLo);
    PH_END();

    // ph5: reads aLo,bLo(buf1) [12]; S5 = A1(t0+2)->buf0; MFMA q00(t1)
    read_a(aLo, buf1, war, llo, lhi);
    read_b(bLo, buf1 + 16384, wbc, llo, lhi);
    stage_half(Ab + 128 * lda, lda, k2a, buf0 + 8192, t);
    LGKM_HINT();
    PH_SYNC();
    mfma_quad(acc[0][0], aLo, bLo);
    PH_END();

    // ph6: reads bHi(buf1) [4]; S6 = A0(t1+2)->buf1; MFMA q01(t1)
    read_b(bHi, buf1 + 24576, wbc, llo, lhi);
    stage_half(Ab, lda, k2b, buf1, t);
    PH_SYNC();
    mfma_quad(acc[0][1], aLo, bHi);
    PH_END();

    // ph7: reads aHi(buf1) [8]; S7 = B0(t1+2)->buf1; MFMA q11(t1)
    read_a(aHi, buf1 + 8192, war, llo, lhi);
    stage_half(Bb, ldb, k2b, buf1 + 16384, t);
    PH_SYNC();
    mfma_quad(acc[1][1], aHi, bHi);
    PH_END();

    // ph8: no reads; S8 = B1(t1+2)->buf1; vmcnt(6); MFMA q10(t1)
    stage_half(Bb + 128 * ldb, ldb, k2b, buf1 + 24576, t);
    PH_SYNC_VM();
    mfma_quad(acc[1][0], aHi, bLo);
    PH_END();
  }

  // epilogue: C/D frag row=(lane>>4)*4+e, col=lane&15; column fold for chunked C
  const long cb = n0 >> cShift;
  const long ncol0 = n0 - (cb << cShift);
  const long czoff = (long)(z >> 2) * sCz4 + (long)(z & 3) * sCz1 + cb * cBatch;
#pragma unroll
  for (int ah = 0; ah < 2; ++ah)
#pragma unroll
    for (int fr = 0; fr < 4; ++fr)
#pragma unroll
      for (int e = 0; e < 4; ++e) {
        const long r = m0 + ah * 128 + wm * 64 + fr * 16 + lhi * 4 + e;
#pragma unroll
        for (int bh2 = 0; bh2 < 2; ++bh2)
#pragma unroll
          for (int fc = 0; fc < 2; ++fc) {
            const long col = ncol0 + bh2 * 128 + wn * 32 + fc * 16 + llo;
            const float val = acc[ah][bh2][fr][fc][e] * scale;
            if (OUT_F32)
              ((float*)Cv)[czoff + r * ldc + col] = val;
            else
              ((u16*)Cv)[czoff + r * ldc + col] = f2bf(val);
          }
      }
}

// ===== 128x64 NT GEMM, BK=64, 4 waves (2x2), double-buffered (R14-proven) ====
template<bool OUT_F32>
__global__ __launch_bounds__(256, 3) void gemm_nt128x64(
    const u16* __restrict__ A, long lda, long sAz,
    const u16* __restrict__ B, long ldb, long sBz,
    void* __restrict__ Cv, long ldc, long sCz,
    int K, float scale)
{
  __shared__ u16 sm[2 * 12288] __attribute__((aligned(16)));  // 48 KiB

  const int t = threadIdx.x;
  XCD_DECODE2(128, 64);
  A += (long)z * sAz + m0 * lda;
  B += (long)z * sBz + n0 * ldb;

  const int wid = t >> 6, lane = t & 63;
  const int lhi = lane >> 4, llo = lane & 15;
  const int wr = (wid >> 1) * 64, wc = (wid & 1) * 32;

  f32x4 acc[4][2] = {};
  const int NT = K >> 6;   // >= 2

  stage_rows256<4>(A, lda, 0, sm, t);
  stage_rows256<2>(B, ldb, 0, sm + 8192, t);
  stage_rows256<4>(A, lda, 64, sm + 12288, t);
  stage_rows256<2>(B, ldb, 64, sm + 12288 + 8192, t);

  for (int kt = 0; kt < NT; ++kt) {
    asm volatile("s_waitcnt vmcnt(6)" ::: "memory");   // tile kt resident (own-wave)
    __builtin_amdgcn_s_barrier();
    asm volatile("" ::: "memory");
    u16* buf = sm + (kt & 1) * 12288;
    bf16x8 af[4][2], bfr[2][2];
#pragma unroll
    for (int i = 0; i < 4; ++i)
#pragma unroll
      for (int kk = 0; kk < 2; ++kk)
        af[i][kk] = frag_ld(buf, wr + i * 16 + llo, (kk << 6) + (lhi << 4));
#pragma unroll
    for (int j = 0; j < 2; ++j)
#pragma unroll
      for (int kk = 0; kk < 2; ++kk)
        bfr[j][kk] = frag_ld(buf + 8192, wc + j * 16 + llo, (kk << 6) + (lhi << 4));
    __builtin_amdgcn_s_setprio(1);
#pragma unroll
    for (int i = 0; i < 4; ++i)
#pragma unroll
      for (int j = 0; j < 2; ++j)
#pragma unroll
        for (int kk = 0; kk < 2; ++kk)
          acc[i][j] = __builtin_amdgcn_mfma_f32_16x16x32_bf16(af[i][kk], bfr[j][kk], acc[i][j], 0, 0, 0);
    __builtin_amdgcn_s_setprio(0);
    asm volatile("" ::: "memory");
    __builtin_amdgcn_s_barrier();
    asm volatile("" ::: "memory");
    const int k2 = ((kt + 2 < NT) ? kt + 2 : kt + 2 - NT) << 6;   // wrapped-dead at tail
    stage_rows256<4>(A, lda, k2, buf, t);
    stage_rows256<2>(B, ldb, k2, buf + 8192, t);
  }

#pragma unroll
  for (int i = 0; i < 4; ++i) {
#pragma unroll
    for (int e = 0; e < 4; ++e) {
      const long r = m0 + wr + i * 16 + lhi * 4 + e;
      if (OUT_F32) {
        float* C = (float*)Cv + (long)z * sCz + r * ldc + n0 + wc + llo;
#pragma unroll
        for (int j = 0; j < 2; ++j) C[j * 16] = acc[i][j][e] * scale;
      } else {
        u16* C = (u16*)Cv + (long)z * sCz + r * ldc + n0 + wc + llo;
#pragma unroll
        for (int j = 0; j < 2; ++j) C[j * 16] = f2bf(acc[i][j][e] * scale);
      }
    }
  }
}

// ---- reduce 4 split-K bf16 partials of G -> bf16 [4][1024][1024] ----
__global__ __launch_bounds__(256) void greduce4b(const u16* __restrict__ gp,
                                                 u16* __restrict__ gb) {
  const long o = (long)blockIdx.x * 256 + threadIdx.x;   // ushort8 index; 512K total
  const long b = o >> 17;
  const long r = o & 131071;
  float s[8] = {};
#pragma unroll
  for (int p = 0; p < 4; ++p) {
    ushort8 u = reinterpret_cast<const ushort8*>(gp)[((b * 4 + p) << 17) + r];
#pragma unroll
    for (int j = 0; j < 8; ++j) s[j] += bf2f(u[j]);
  }
  ushort8 out;
#pragma unroll
  for (int j = 0; j < 8; ++j) out[j] = f2bf(s[j]);
  reinterpret_cast<ushort8*>(gb)[o] = out;
}

// ---- single-pass row softmax: att f32 [4096][1024] -> P bf16 ----
__global__ __launch_bounds__(256) void softmax1(const float* __restrict__ att,
                                                u16* __restrict__ P) {
  const long row = blockIdx.x;
  const int t = threadIdx.x;
  float4 v = reinterpret_cast<const float4*>(att + row * 1024)[t];
  float m = fmaxf(fmaxf(v.x, v.y), fmaxf(v.z, v.w));
#pragma unroll
  for (int off = 32; off > 0; off >>= 1) m = fmaxf(m, __shfl_down(m, off, 64));
  __shared__ float smax[4], ssum[4];
  const int wid = t >> 6, lane = t & 63;
  if (lane == 0) smax[wid] = m;
  __syncthreads();
  m = fmaxf(fmaxf(smax[0], smax[1]), fmaxf(smax[2], smax[3]));
  float e0 = expf(v.x - m), e1 = expf(v.y - m), e2 = expf(v.z - m), e3 = expf(v.w - m);
  float s = e0 + e1 + e2 + e3;
#pragma unroll
  for (int off = 32; off > 0; off >>= 1) s += __shfl_down(s, off, 64);
  if (lane == 0) ssum[wid] = s;
  __syncthreads();
  s = ssum[0] + ssum[1] + ssum[2] + ssum[3];
  float inv = 1.0f / s;
  ushort4 o;
  o.x = f2bf(e0 * inv); o.y = f2bf(e1 * inv); o.z = f2bf(e2 * inv); o.w = f2bf(e3 * inv);
  reinterpret_cast<ushort4*>(P + row * 1024)[t] = o;
}

extern "C" void kernel_launch(void* const* d_in, const int* in_sizes, int n_in,
                              void* d_out, int out_size, void* d_ws, size_t ws_size,
                              hipStream_t stream) {
  const float* x  = (const float*)d_in[0];
  const float* Wq = (const float*)d_in[1];
  const float* Wk = (const float*)d_in[2];
  const float* Wv = (const float*)d_in[3];
  const float* Wo = (const float*)d_in[4];

  const long M1 = 1L << 20;               // 1M elements

  // workspace layout (u16 elements)
  u16* xbf    = (u16*)d_ws;               // [16384][1024]                      16M
  u16* wq     = xbf + 16 * M1;            //                                     1M
  u16* wk     = wq + M1;                  //                                     1M
  u16* wv     = wk + M1;                  //                                     1M
  u16* wo     = wv + M1;                  //                                     1M
  u16* wvT    = wo + M1;                  // Wv^T                                1M
  u16* xT     = wvT + M1;                 // [4][1024 feat][4096 tok]           16M
  u16* gbf    = xT + 16 * M1;             // G bf16 [4][1024][1024]              4M
  u16* tbuf   = gbf + 4 * M1;             // T~ = Wq G                           4M
  u16* pbuf   = tbuf + 4 * M1;            // P (softmax)                         4M
  u16* rtb    = pbuf + 4 * M1;            // R^T                                 4M
  u16* sbuf   = rtb + 4 * M1;             // S = Wo R                            4M
  u16* gpartb = sbuf + 4 * M1;            // G bf16 partials [16][1024][1024]   16M
  float* attf = (float*)d_out;            // att f32 [4][1024][1024] (16 MB)

  dim3 b256(256), b512(512);
  const long NOF = 0;
  const int NSH = 30;

  // conversions + transposes
  cvt_x_dual<<<dim3(16, 64, 4), b256, 0, stream>>>(x, xbf, xT);
  cvt_w4<<<dim3(4096), b256, 0, stream>>>(Wq, Wk, Wv, Wo, wq, wk, wv, wo);
  transpose_bf16<<<dim3(16, 16, 1), b256, 0, stream>>>(wv, 1024, 0, wvT, 1024, 0);

  // G[b] = x[b]^T x[b]  (M=N=1024, K=4096 split 4; z=b*4+p) -> bf16 partials
  gemm_nt256<false><<<dim3(4, 4, 16), b512, 0, stream>>>(
      xT, 4096, 1024L * 4096, 1024, xT, 4096, 1024L * 4096, 1024,
      (void*)gpartb, 1024, 4L << 20, 1L << 20, NOF, NSH, 1024, 1.0f);
  greduce4b<<<dim3(2048), b256, 0, stream>>>(gpartb, gbf);

  // T~[b] = Wq G[b]   (G symmetric -> NT form)
  gemm_nt128x64<false><<<dim3(8, 16, 4), b256, 0, stream>>>(
      wq, 1024, 0, gbf, 1024, M1, (void*)tbuf, 1024, M1, 1024, 1.0f);
  // att[b] = T~[b] Wk^T / 32 -> f32 in d_out
  gemm_nt128x64<true><<<dim3(8, 16, 4), b256, 0, stream>>>(
      tbuf, 1024, M1, wk, 1024, 0, (void*)attf, 1024, M1, 1024, 1.0f / 32.0f);
  // softmax rows -> P bf16
  softmax1<<<dim3(4096), b256, 0, stream>>>(attf, pbuf);

  // R^T[b]: C[e,k] = sum_j Wv[j,e] P[k,j]
  gemm_nt128x64<false><<<dim3(8, 16, 4), b256, 0, stream>>>(
      wvT, 1024, 0, pbuf, 1024, M1, (void*)rtb, 1024, M1, 1024, 1.0f);
  // S[b]: C[e',e] = sum_k Wo[e',k] RT[e,k]
  gemm_nt128x64<false><<<dim3(8, 16, 4), b256, 0, stream>>>(
      wo, 1024, 0, rtb, 1024, M1, (void*)sbuf, 1024, M1, 1024, 1.0f);

  // final[b] = x[b] S[b]^T  (M=4096/batch, N=1024, K=1024) -> d_out f32
  gemm_nt256<true><<<dim3(16, 4, 4), b512, 0, stream>>>(
      xbf, 1024, 0, 4096L * 1024, sbuf, 1024, 0, M1,
      d_out, 1024, 0, 4096L * 1024, NOF, NSH, 1024, 1.0f);
}

// Round 17
// 183.612 us; speedup vs baseline: 1.0381x; 1.0381x over previous
//
#include <hip/hip_runtime.h>
#include <hip/hip_bf16.h>

typedef unsigned short u16;
typedef __bf16 bf16x8 __attribute__((ext_vector_type(8)));
typedef float f32x4 __attribute__((ext_vector_type(4)));
typedef unsigned short ushort8 __attribute__((ext_vector_type(8)));

#define AS1 __attribute__((address_space(1)))
#define AS3 __attribute__((address_space(3)))

__device__ inline u16 f2bf(float f) {
  union { float f; unsigned int u; } c; c.f = f;
  unsigned int u = c.u;
  return (u16)((u + 0x7fffu + ((u >> 16) & 1u)) >> 16);
}
__device__ inline float bf2f(u16 v) {
  union { unsigned int u; float f; } c; c.u = ((unsigned int)v) << 16;
  return c.f;
}

// ---------------- fused x conversion + transpose ----------------
__global__ __launch_bounds__(256) void cvt_x_dual(const float* __restrict__ x,
                                                  u16* __restrict__ xbf,
                                                  u16* __restrict__ xT) {
  __shared__ u16 tile[64][68];
  const int t = threadIdx.x;
  const long e0 = (long)blockIdx.x * 64;     // feature tile
  const long l0 = (long)blockIdx.y * 64;     // token tile within batch
  const long b  = blockIdx.z;
  const int tr = t >> 4, tc = t & 15;
#pragma unroll
  for (int i = 0; i < 4; ++i) {
    const int r = tr + i * 16;
    const long gl = b * 4096 + l0 + r;
    float4 v = *reinterpret_cast<const float4*>(x + gl * 1024 + e0 + tc * 4);
    ushort4 o;
    o.x = f2bf(v.x); o.y = f2bf(v.y); o.z = f2bf(v.z); o.w = f2bf(v.w);
    *reinterpret_cast<ushort4*>(xbf + gl * 1024 + e0 + tc * 4) = o;
    *reinterpret_cast<ushort4*>(&tile[r][tc * 4]) = o;
  }
  __syncthreads();
#pragma unroll
  for (int i = 0; i < 4; ++i) {
    const int c = tr + i * 16;
    ushort4 o;
    o.x = tile[tc * 4 + 0][c]; o.y = tile[tc * 4 + 1][c];
    o.z = tile[tc * 4 + 2][c]; o.w = tile[tc * 4 + 3][c];
    *reinterpret_cast<ushort4*>(xT + b * (1024L * 4096) + (e0 + c) * 4096 + l0 + tc * 4) = o;
  }
}

// ---------------- fused conversion of the 4 weight matrices ----------------
__global__ __launch_bounds__(256) void cvt_w4(const float* __restrict__ a, const float* __restrict__ b,
                                              const float* __restrict__ c, const float* __restrict__ d,
                                              u16* __restrict__ oa, u16* __restrict__ ob,
                                              u16* __restrict__ oc, u16* __restrict__ od) {
  int i = blockIdx.x * 256 + threadIdx.x;
  const int which = i >> 18;
  const int j = i & 262143;
  const float* src = which == 0 ? a : which == 1 ? b : which == 2 ? c : d;
  u16* dst = which == 0 ? oa : which == 1 ? ob : which == 2 ? oc : od;
  float4 v = reinterpret_cast<const float4*>(src)[j];
  ushort4 o;
  o.x = f2bf(v.x); o.y = f2bf(v.y); o.z = f2bf(v.z); o.w = f2bf(v.w);
  reinterpret_cast<ushort4*>(dst)[j] = o;
}

// ---------------- bf16 tiled transpose ----------------
__global__ __launch_bounds__(256) void transpose_bf16(
    const u16* __restrict__ src, long sLd, long sZ,
    u16* __restrict__ dst, long dLd, long dZ) {
  __shared__ u16 tile[64][68];
  const int t = threadIdx.x;
  const long r0 = (long)blockIdx.y * 64;
  const long c0 = (long)blockIdx.x * 64;
  const long z = blockIdx.z;
  const int tr = t >> 4, tc = t & 15;
#pragma unroll
  for (int i = 0; i < 4; ++i) {
    const int r = tr + i * 16;
    ushort4 v = *reinterpret_cast<const ushort4*>(src + z * sZ + (r0 + r) * sLd + c0 + tc * 4);
    *reinterpret_cast<ushort4*>(&tile[r][tc * 4]) = v;
  }
  __syncthreads();
#pragma unroll
  for (int i = 0; i < 4; ++i) {
    const int c = tr + i * 16;
    ushort4 o;
    o.x = tile[tc * 4 + 0][c]; o.y = tile[tc * 4 + 1][c];
    o.z = tile[tc * 4 + 2][c]; o.w = tile[tc * 4 + 3][c];
    *reinterpret_cast<ushort4*>(dst + z * dZ + (c0 + c) * dLd + r0 + tc * 4) = o;
  }
}

// ---- staging helpers via gload_lds (pre-swizzled source) ----
__device__ __forceinline__ void stage_half(const u16* __restrict__ g, long ld, int k0,
                                           u16* dst, int t) {
#pragma unroll
  for (int i = 0; i < 2; ++i) {
    const int c = i * 512 + t;
    const int r = c >> 3;
    const int s = c & 7;
    const int col = ((s ^ (r & 7)) << 3) + k0;
    __builtin_amdgcn_global_load_lds((const AS1 void*)(g + (long)r * ld + col),
                                     (AS3 void*)(dst + c * 8), 16, 0, 0);
  }
}

// 256-thread variant: N16 chunks per thread (rows = N16*256/8)
template<int N16>
__device__ __forceinline__ void stage_rows256(const u16* __restrict__ g, long ld, int k0,
                                              u16* dst, int t) {
#pragma unroll
  for (int i = 0; i < N16; ++i) {
    const int c = i * 256 + t;
    const int r = c >> 3;
    const int s = c & 7;
    const int col = ((s ^ (r & 7)) << 3) + k0;
    __builtin_amdgcn_global_load_lds((const AS1 void*)(g + (long)r * ld + col),
                                     (AS3 void*)(dst + c * 8), 16, 0, 0);
  }
}

__device__ __forceinline__ bf16x8 frag_ld(const u16* s, int row, int colb) {
  return *reinterpret_cast<const bf16x8*>(
      reinterpret_cast<const char*>(s) + row * 128 + (colb ^ ((row & 7) << 4)));
}

// ---- flattened bijective XCD swizzle (total % 8 == 0 at all call sites) ----
#define XCD_DECODE2(TM, TN)                                                  \
  const int nxy = gridDim.x * gridDim.y;                                     \
  int flat = blockIdx.x + gridDim.x * blockIdx.y + nxy * blockIdx.z;         \
  const int total = nxy * gridDim.z;                                         \
  const int qq = total >> 3;                                                 \
  flat = (flat & 7) * qq + (flat >> 3);                                      \
  const int z = flat / nxy;                                                  \
  const int wg = flat % nxy;                                                 \
  const long m0 = (long)(wg % gridDim.x) * (TM);                             \
  const long n0 = (long)(wg / gridDim.x) * (TN);

// ============ 256x256 NT GEMM, BK=64, 8 waves, 4-phase, vmcnt(6)/phase ========
// R15 engine (session best): read-balance 0/4/8/12; ph3 pre-reads NEXT tile's
// A-lo + B-lo into persistent registers so ph0 has zero ds_reads.
#define BAR_PRE()       do { asm volatile("s_waitcnt vmcnt(6)" ::: "memory"); \
                             __builtin_amdgcn_s_barrier(); \
                             asm volatile("" ::: "memory"); } while (0)
#define BAR_POST()      do { asm volatile("" ::: "memory"); \
                             __builtin_amdgcn_s_barrier(); \
                             asm volatile("" ::: "memory"); } while (0)

template<bool OUT_F32>
__global__ __launch_bounds__(512, 2) void gemm_nt256(
    const u16* __restrict__ A, long lda, long sAz4, long sAz1,
    const u16* __restrict__ B, long ldb, long sBz4, long sBz1,
    void* __restrict__ Cv, long ldc, long sCz4, long sCz1,
    long cBatch, int cShift,
    int K, float scale)
{
  __shared__ u16 sm[2 * 32768] __attribute__((aligned(16)));  // 128 KiB

  const int t = threadIdx.x;
  XCD_DECODE2(256, 256);
  const long azoff = (long)(z >> 2) * sAz4 + (long)(z & 3) * sAz1;
  const long bzoff = (long)(z >> 2) * sBz4 + (long)(z & 3) * sBz1;
  const u16* Ab = A + azoff + m0 * lda;
  const u16* Bb = B + bzoff + n0 * ldb;

  const int wid = t >> 6, lane = t & 63;
  const int lhi = lane >> 4, llo = lane & 15;
  const int wm = wid >> 2, wn = wid & 3;

  f32x4 acc[2][4][2][2] = {};
  bf16x8 aLo[4][2], bl[2][2];    // persistent across iterations
  const int NT = K >> 6;

  stage_half(Ab, lda, 0, sm, t);
  stage_half(Bb + 128 * ldb, ldb, 0, sm + 16384 + 8192, t);
  stage_half(Bb, ldb, 0, sm + 16384, t);
  stage_half(Ab + 128 * lda, lda, 0, sm + 8192, t);
  stage_half(Ab, lda, 64, sm + 32768, t);
  stage_half(Bb + 128 * ldb, ldb, 64, sm + 32768 + 16384 + 8192, t);
  asm volatile("s_waitcnt vmcnt(4)" ::: "memory");
  __builtin_amdgcn_s_barrier();
  asm volatile("" ::: "memory");
  // pre-read tile0's A-lo + B-lo
#pragma unroll
  for (int fr = 0; fr < 4; ++fr)
#pragma unroll
    for (int kk = 0; kk < 2; ++kk)
      aLo[fr][kk] = frag_ld(sm, wm * 64 + fr * 16 + llo, (kk << 6) + (lhi << 4));
#pragma unroll
  for (int fc = 0; fc < 2; ++fc)
#pragma unroll
    for (int kk = 0; kk < 2; ++kk)
      bl[fc][kk] = frag_ld(sm + 16384, wn * 32 + fc * 16 + llo, (kk << 6) + (lhi << 4));

  for (int kt = 0; kt < NT; ++kt) {
    const int kb = kt & 1;
    u16* bc = sm + kb * 32768;
    u16* bn = sm + (kb ^ 1) * 32768;
    const u16* sAc = bc;
    const u16* sBc = bc + 16384;
    const int k1 = ((kt + 1 < NT) ? kt + 1 : 0) << 6;
    const int k2 = ((kt + 2 < NT) ? kt + 2 : kt + 2 - NT) << 6;

    bf16x8 aHi[4][2], bh[2][2];

    // ph0: stage B0(t+1); NO ds_reads; MFMA (Alo,Blo) from persistent regs
    stage_half(Bb, ldb, k1, bn + 16384, t);
    BAR_PRE();
    __builtin_amdgcn_s_setprio(1);
#pragma unroll
    for (int fr = 0; fr < 4; ++fr)
#pragma unroll
      for (int fc = 0; fc < 2; ++fc)
#pragma unroll
        for (int kk = 0; kk < 2; ++kk)
          acc[0][fr][0][fc] = __builtin_amdgcn_mfma_f32_16x16x32_bf16(aLo[fr][kk], bl[fc][kk], acc[0][fr][0][fc], 0, 0, 0);
    __builtin_amdgcn_s_setprio(0);
    BAR_POST();

    // ph1: read B-hi(4); stage A1(t+1); MFMA (Alo,Bhi)
#pragma unroll
    for (int fc = 0; fc < 2; ++fc)
#pragma unroll
      for (int kk = 0; kk < 2; ++kk)
        bh[fc][kk] = frag_ld(sBc, 128 + wn * 32 + fc * 16 + llo, (kk << 6) + (lhi << 4));
    stage_half(Ab + 128 * lda, lda, k1, bn + 8192, t);
    BAR_PRE();
    __builtin_amdgcn_s_setprio(1);
#pragma unroll
    for (int fr = 0; fr < 4; ++fr)
#pragma unroll
      for (int fc = 0; fc < 2; ++fc)
#pragma unroll
        for (int kk = 0; kk < 2; ++kk)
          acc[0][fr][1][fc] = __builtin_amdgcn_mfma_f32_16x16x32_bf16(aLo[fr][kk], bh[fc][kk], acc[0][fr][1][fc], 0, 0, 0);
    __builtin_amdgcn_s_setprio(0);
    BAR_POST();

    // ph2: read A-hi(8); stage A0(t+2); MFMA (Ahi,Bhi)
#pragma unroll
    for (int fr = 0; fr < 4; ++fr)
#pragma unroll
      for (int kk = 0; kk < 2; ++kk)
        aHi[fr][kk] = frag_ld(sAc, 128 + wm * 64 + fr * 16 + llo, (kk << 6) + (lhi << 4));
    stage_half(Ab, lda, k2, bc, t);
    BAR_PRE();
    __builtin_amdgcn_s_setprio(1);
#pragma unroll
    for (int fr = 0; fr < 4; ++fr)
#pragma unroll
      for (int fc = 0; fc < 2; ++fc)
#pragma unroll
        for (int kk = 0; kk < 2; ++kk)
          acc[1][fr][1][fc] = __builtin_amdgcn_mfma_f32_16x16x32_bf16(aHi[fr][kk], bh[fc][kk], acc[1][fr][1][fc], 0, 0, 0);
    __builtin_amdgcn_s_setprio(0);
    BAR_POST();

    // ph3: stage B1(t+2); BAR_PRE retires B0(t+1); MFMA (Ahi,Blo);
    //      then pre-read NEXT tile's A-lo + B-lo (latency spans 2 barriers)
    stage_half(Bb + 128 * ldb, ldb, k2, bc + 16384 + 8192, t);
    BAR_PRE();
    __builtin_amdgcn_s_setprio(1);
#pragma unroll
    for (int fr = 0; fr < 4; ++fr)
#pragma unroll
      for (int fc = 0; fc < 2; ++fc)
#pragma unroll
        for (int kk = 0; kk < 2; ++kk)
          acc[1][fr][0][fc] = __builtin_amdgcn_mfma_f32_16x16x32_bf16(aHi[fr][kk], bl[fc][kk], acc[1][fr][0][fc], 0, 0, 0);
    __builtin_amdgcn_s_setprio(0);
#pragma unroll
    for (int fr = 0; fr < 4; ++fr)
#pragma unroll
      for (int kk = 0; kk < 2; ++kk)
        aLo[fr][kk] = frag_ld(bn, wm * 64 + fr * 16 + llo, (kk << 6) + (lhi << 4));
#pragma unroll
    for (int fc = 0; fc < 2; ++fc)
#pragma unroll
      for (int kk = 0; kk < 2; ++kk)
        bl[fc][kk] = frag_ld(bn + 16384, wn * 32 + fc * 16 + llo, (kk << 6) + (lhi << 4));
    BAR_POST();
  }

  const long cb = n0 >> cShift;
  const long ncol0 = n0 - (cb << cShift);
  const long czoff = (long)(z >> 2) * sCz4 + (long)(z & 3) * sCz1 + cb * cBatch;
#pragma unroll
  for (int ah = 0; ah < 2; ++ah)
#pragma unroll
    for (int fr = 0; fr < 4; ++fr)
#pragma unroll
      for (int e = 0; e < 4; ++e) {
        const long r = m0 + ah * 128 + wm * 64 + fr * 16 + lhi * 4 + e;
#pragma unroll
        for (int bh2 = 0; bh2 < 2; ++bh2)
#pragma unroll
          for (int fc = 0; fc < 2; ++fc) {
            const long col = ncol0 + bh2 * 128 + wn * 32 + fc * 16 + llo;
            const float val = acc[ah][fr][bh2][fc][e] * scale;
            if (OUT_F32)
              ((float*)Cv)[czoff + r * ldc + col] = val;
            else
              ((u16*)Cv)[czoff + r * ldc + col] = f2bf(val);
          }
      }
}

// ===== 128x64 NT GEMM, BK=64, 4 waves (2x2), double-buffered (R14-proven) ====
template<bool OUT_F32>
__global__ __launch_bounds__(256, 3) void gemm_nt128x64(
    const u16* __restrict__ A, long lda, long sAz,
    const u16* __restrict__ B, long ldb, long sBz,
    void* __restrict__ Cv, long ldc, long sCz,
    int K, float scale)
{
  __shared__ u16 sm[2 * 12288] __attribute__((aligned(16)));  // 48 KiB

  const int t = threadIdx.x;
  XCD_DECODE2(128, 64);
  A += (long)z * sAz + m0 * lda;
  B += (long)z * sBz + n0 * ldb;

  const int wid = t >> 6, lane = t & 63;
  const int lhi = lane >> 4, llo = lane & 15;
  const int wr = (wid >> 1) * 64, wc = (wid & 1) * 32;

  f32x4 acc[4][2] = {};
  const int NT = K >> 6;   // >= 2

  stage_rows256<4>(A, lda, 0, sm, t);
  stage_rows256<2>(B, ldb, 0, sm + 8192, t);
  stage_rows256<4>(A, lda, 64, sm + 12288, t);
  stage_rows256<2>(B, ldb, 64, sm + 12288 + 8192, t);

  for (int kt = 0; kt < NT; ++kt) {
    asm volatile("s_waitcnt vmcnt(6)" ::: "memory");   // tile kt resident (own-wave)
    __builtin_amdgcn_s_barrier();
    asm volatile("" ::: "memory");
    u16* buf = sm + (kt & 1) * 12288;
    bf16x8 af[4][2], bfr[2][2];
#pragma unroll
    for (int i = 0; i < 4; ++i)
#pragma unroll
      for (int kk = 0; kk < 2; ++kk)
        af[i][kk] = frag_ld(buf, wr + i * 16 + llo, (kk << 6) + (lhi << 4));
#pragma unroll
    for (int j = 0; j < 2; ++j)
#pragma unroll
      for (int kk = 0; kk < 2; ++kk)
        bfr[j][kk] = frag_ld(buf + 8192, wc + j * 16 + llo, (kk << 6) + (lhi << 4));
    __builtin_amdgcn_s_setprio(1);
#pragma unroll
    for (int i = 0; i < 4; ++i)
#pragma unroll
      for (int j = 0; j < 2; ++j)
#pragma unroll
        for (int kk = 0; kk < 2; ++kk)
          acc[i][j] = __builtin_amdgcn_mfma_f32_16x16x32_bf16(af[i][kk], bfr[j][kk], acc[i][j], 0, 0, 0);
    __builtin_amdgcn_s_setprio(0);
    asm volatile("" ::: "memory");
    __builtin_amdgcn_s_barrier();
    asm volatile("" ::: "memory");
    const int k2 = ((kt + 2 < NT) ? kt + 2 : kt + 2 - NT) << 6;   // wrapped-dead at tail
    stage_rows256<4>(A, lda, k2, buf, t);
    stage_rows256<2>(B, ldb, k2, buf + 8192, t);
  }

#pragma unroll
  for (int i = 0; i < 4; ++i) {
#pragma unroll
    for (int e = 0; e < 4; ++e) {
      const long r = m0 + wr + i * 16 + lhi * 4 + e;
      if (OUT_F32) {
        float* C = (float*)Cv + (long)z * sCz + r * ldc + n0 + wc + llo;
#pragma unroll
        for (int j = 0; j < 2; ++j) C[j * 16] = acc[i][j][e] * scale;
      } else {
        u16* C = (u16*)Cv + (long)z * sCz + r * ldc + n0 + wc + llo;
#pragma unroll
        for (int j = 0; j < 2; ++j) C[j * 16] = f2bf(acc[i][j][e] * scale);
      }
    }
  }
}

// ---- reduce 4 split-K bf16 partials of G -> bf16 [4][1024][1024] ----
__global__ __launch_bounds__(256) void greduce4b(const u16* __restrict__ gp,
                                                 u16* __restrict__ gb) {
  const long o = (long)blockIdx.x * 256 + threadIdx.x;   // ushort8 index; 512K total
  const long b = o >> 17;
  const long r = o & 131071;
  float s[8] = {};
#pragma unroll
  for (int p = 0; p < 4; ++p) {
    ushort8 u = reinterpret_cast<const ushort8*>(gp)[((b * 4 + p) << 17) + r];
#pragma unroll
    for (int j = 0; j < 8; ++j) s[j] += bf2f(u[j]);
  }
  ushort8 out;
#pragma unroll
  for (int j = 0; j < 8; ++j) out[j] = f2bf(s[j]);
  reinterpret_cast<ushort8*>(gb)[o] = out;
}

// ---- single-pass row softmax: att f32 [4096][1024] -> P bf16 ----
__global__ __launch_bounds__(256) void softmax1(const float* __restrict__ att,
                                                u16* __restrict__ P) {
  const long row = blockIdx.x;
  const int t = threadIdx.x;
  float4 v = reinterpret_cast<const float4*>(att + row * 1024)[t];
  float m = fmaxf(fmaxf(v.x, v.y), fmaxf(v.z, v.w));
#pragma unroll
  for (int off = 32; off > 0; off >>= 1) m = fmaxf(m, __shfl_down(m, off, 64));
  __shared__ float smax[4], ssum[4];
  const int wid = t >> 6, lane = t & 63;
  if (lane == 0) smax[wid] = m;
  __syncthreads();
  m = fmaxf(fmaxf(smax[0], smax[1]), fmaxf(smax[2], smax[3]));
  float e0 = expf(v.x - m), e1 = expf(v.y - m), e2 = expf(v.z - m), e3 = expf(v.w - m);
  float s = e0 + e1 + e2 + e3;
#pragma unroll
  for (int off = 32; off > 0; off >>= 1) s += __shfl_down(s, off, 64);
  if (lane == 0) ssum[wid] = s;
  __syncthreads();
  s = ssum[0] + ssum[1] + ssum[2] + ssum[3];
  float inv = 1.0f / s;
  ushort4 o;
  o.x = f2bf(e0 * inv); o.y = f2bf(e1 * inv); o.z = f2bf(e2 * inv); o.w = f2bf(e3 * inv);
  reinterpret_cast<ushort4*>(P + row * 1024)[t] = o;
}

extern "C" void kernel_launch(void* const* d_in, const int* in_sizes, int n_in,
                              void* d_out, int out_size, void* d_ws, size_t ws_size,
                              hipStream_t stream) {
  const float* x  = (const float*)d_in[0];
  const float* Wq = (const float*)d_in[1];
  const float* Wk = (const float*)d_in[2];
  const float* Wv = (const float*)d_in[3];
  const float* Wo = (const float*)d_in[4];

  const long M1 = 1L << 20;               // 1M elements

  // workspace layout (u16 elements)
  u16* xbf    = (u16*)d_ws;               // [16384][1024]                      16M
  u16* wq     = xbf + 16 * M1;            //                                     1M
  u16* wk     = wq + M1;                  //                                     1M
  u16* wv     = wk + M1;                  //                                     1M
  u16* wo     = wv + M1;                  //                                     1M
  u16* wvT    = wo + M1;                  // Wv^T                                1M
  u16* xT     = wvT + M1;                 // [4][1024 feat][4096 tok]           16M
  u16* gbf    = xT + 16 * M1;             // G bf16 [4][1024][1024]              4M
  u16* tbuf   = gbf + 4 * M1;             // T~ = Wq G                           4M
  u16* pbuf   = tbuf + 4 * M1;            // P (softmax)                         4M
  u16* rtb    = pbuf + 4 * M1;            // R^T                                 4M
  u16* sbuf   = rtb + 4 * M1;             // S = Wo R                            4M
  u16* gpartb = sbuf + 4 * M1;            // G bf16 partials [16][1024][1024]   16M
  float* attf = (float*)d_out;            // att f32 [4][1024][1024] (16 MB)

  dim3 b256(256), b512(512);
  const long NOF = 0;
  const int NSH = 30;

  // conversions + transposes
  cvt_x_dual<<<dim3(16, 64, 4), b256, 0, stream>>>(x, xbf, xT);
  cvt_w4<<<dim3(4096), b256, 0, stream>>>(Wq, Wk, Wv, Wo, wq, wk, wv, wo);
  transpose_bf16<<<dim3(16, 16, 1), b256, 0, stream>>>(wv, 1024, 0, wvT, 1024, 0);

  // G[b] = x[b]^T x[b]  (M=N=1024, K=4096 split 4; z=b*4+p) -> bf16 partials
  gemm_nt256<false><<<dim3(4, 4, 16), b512, 0, stream>>>(
      xT, 4096, 1024L * 4096, 1024, xT, 4096, 1024L * 4096, 1024,
      (void*)gpartb, 1024, 4L << 20, 1L << 20, NOF, NSH, 1024, 1.0f);
  greduce4b<<<dim3(2048), b256, 0, stream>>>(gpartb, gbf);

  // T~[b] = Wq G[b]   (G symmetric -> NT form)
  gemm_nt128x64<false><<<dim3(8, 16, 4), b256, 0, stream>>>(
      wq, 1024, 0, gbf, 1024, M1, (void*)tbuf, 1024, M1, 1024, 1.0f);
  // att[b] = T~[b] Wk^T / 32 -> f32 in d_out
  gemm_nt128x64<true><<<dim3(8, 16, 4), b256, 0, stream>>>(
      tbuf, 1024, M1, wk, 1024, 0, (void*)attf, 1024, M1, 1024, 1.0f / 32.0f);
  // softmax rows -> P bf16
  softmax1<<<dim3(4096), b256, 0, stream>>>(attf, pbuf);

  // R^T[b]: C[e,k] = sum_j Wv[j,e] P[k,j]
  gemm_nt128x64<false><<<dim3(8, 16, 4), b256, 0, stream>>>(
      wvT, 1024, 0, pbuf, 1024, M1, (void*)rtb, 1024, M1, 1024, 1.0f);
  // S[b]: C[e',e] = sum_k Wo[e',k] RT[e,k]
  gemm_nt128x64<false><<<dim3(8, 16, 4), b256, 0, stream>>>(
      wo, 1024, 0, rtb, 1024, M1, (void*)sbuf, 1024, M1, 1024, 1.0f);

  // final[b] = x[b] S[b]^T  (M=4096/batch, N=1024, K=1024) -> d_out f32
  gemm_nt256<true><<<dim3(16, 4, 4), b512, 0, stream>>>(
      xbf, 1024, 0, 4096L * 1024, sbuf, 1024, 0, M1,
      d_out, 1024, 0, 4096L * 1024, NOF, NSH, 1024, 1.0f);
}

// Round 18
// 182.694 us; speedup vs baseline: 1.0433x; 1.0050x over previous
//
#include <hip/hip_runtime.h>
#include <hip/hip_bf16.h>

typedef unsigned short u16;
typedef __bf16 bf16x8 __attribute__((ext_vector_type(8)));
typedef float f32x4 __attribute__((ext_vector_type(4)));
typedef unsigned short ushort8 __attribute__((ext_vector_type(8)));

#define AS1 __attribute__((address_space(1)))
#define AS3 __attribute__((address_space(3)))

__device__ inline u16 f2bf(float f) {
  union { float f; unsigned int u; } c; c.f = f;
  unsigned int u = c.u;
  return (u16)((u + 0x7fffu + ((u >> 16) & 1u)) >> 16);
}
__device__ inline float bf2f(u16 v) {
  union { unsigned int u; float f; } c; c.u = ((unsigned int)v) << 16;
  return c.f;
}

// ---------------- fused x conversion + transpose ----------------
__global__ __launch_bounds__(256) void cvt_x_dual(const float* __restrict__ x,
                                                  u16* __restrict__ xbf,
                                                  u16* __restrict__ xT) {
  __shared__ u16 tile[64][68];
  const int t = threadIdx.x;
  const long e0 = (long)blockIdx.x * 64;     // feature tile
  const long l0 = (long)blockIdx.y * 64;     // token tile within batch
  const long b  = blockIdx.z;
  const int tr = t >> 4, tc = t & 15;
#pragma unroll
  for (int i = 0; i < 4; ++i) {
    const int r = tr + i * 16;
    const long gl = b * 4096 + l0 + r;
    float4 v = *reinterpret_cast<const float4*>(x + gl * 1024 + e0 + tc * 4);
    ushort4 o;
    o.x = f2bf(v.x); o.y = f2bf(v.y); o.z = f2bf(v.z); o.w = f2bf(v.w);
    *reinterpret_cast<ushort4*>(xbf + gl * 1024 + e0 + tc * 4) = o;
    *reinterpret_cast<ushort4*>(&tile[r][tc * 4]) = o;
  }
  __syncthreads();
#pragma unroll
  for (int i = 0; i < 4; ++i) {
    const int c = tr + i * 16;
    ushort4 o;
    o.x = tile[tc * 4 + 0][c]; o.y = tile[tc * 4 + 1][c];
    o.z = tile[tc * 4 + 2][c]; o.w = tile[tc * 4 + 3][c];
    *reinterpret_cast<ushort4*>(xT + b * (1024L * 4096) + (e0 + c) * 4096 + l0 + tc * 4) = o;
  }
}

// ---------------- fused conversion of the 4 weight matrices ----------------
__global__ __launch_bounds__(256) void cvt_w4(const float* __restrict__ a, const float* __restrict__ b,
                                              const float* __restrict__ c, const float* __restrict__ d,
                                              u16* __restrict__ oa, u16* __restrict__ ob,
                                              u16* __restrict__ oc, u16* __restrict__ od) {
  int i = blockIdx.x * 256 + threadIdx.x;
  const int which = i >> 18;
  const int j = i & 262143;
  const float* src = which == 0 ? a : which == 1 ? b : which == 2 ? c : d;
  u16* dst = which == 0 ? oa : which == 1 ? ob : which == 2 ? oc : od;
  float4 v = reinterpret_cast<const float4*>(src)[j];
  ushort4 o;
  o.x = f2bf(v.x); o.y = f2bf(v.y); o.z = f2bf(v.z); o.w = f2bf(v.w);
  reinterpret_cast<ushort4*>(dst)[j] = o;
}

// ---------------- bf16 tiled transpose ----------------
__global__ __launch_bounds__(256) void transpose_bf16(
    const u16* __restrict__ src, long sLd, long sZ,
    u16* __restrict__ dst, long dLd, long dZ) {
  __shared__ u16 tile[64][68];
  const int t = threadIdx.x;
  const long r0 = (long)blockIdx.y * 64;
  const long c0 = (long)blockIdx.x * 64;
  const long z = blockIdx.z;
  const int tr = t >> 4, tc = t & 15;
#pragma unroll
  for (int i = 0; i < 4; ++i) {
    const int r = tr + i * 16;
    ushort4 v = *reinterpret_cast<const ushort4*>(src + z * sZ + (r0 + r) * sLd + c0 + tc * 4);
    *reinterpret_cast<ushort4*>(&tile[r][tc * 4]) = v;
  }
  __syncthreads();
#pragma unroll
  for (int i = 0; i < 4; ++i) {
    const int c = tr + i * 16;
    ushort4 o;
    o.x = tile[tc * 4 + 0][c]; o.y = tile[tc * 4 + 1][c];
    o.z = tile[tc * 4 + 2][c]; o.w = tile[tc * 4 + 3][c];
    *reinterpret_cast<ushort4*>(dst + z * dZ + (c0 + c) * dLd + r0 + tc * 4) = o;
  }
}

// ---- staging helpers via gload_lds (pre-swizzled source) ----
__device__ __forceinline__ void stage_half(const u16* __restrict__ g, long ld, int k0,
                                           u16* dst, int t) {
#pragma unroll
  for (int i = 0; i < 2; ++i) {
    const int c = i * 512 + t;
    const int r = c >> 3;
    const int s = c & 7;
    const int col = ((s ^ (r & 7)) << 3) + k0;
    __builtin_amdgcn_global_load_lds((const AS1 void*)(g + (long)r * ld + col),
                                     (AS3 void*)(dst + c * 8), 16, 0, 0);
  }
}

// 256-thread variant: N16 chunks per thread (rows = N16*256/8)
template<int N16>
__device__ __forceinline__ void stage_rows256(const u16* __restrict__ g, long ld, int k0,
                                              u16* dst, int t) {
#pragma unroll
  for (int i = 0; i < N16; ++i) {
    const int c = i * 256 + t;
    const int r = c >> 3;
    const int s = c & 7;
    const int col = ((s ^ (r & 7)) << 3) + k0;
    __builtin_amdgcn_global_load_lds((const AS1 void*)(g + (long)r * ld + col),
                                     (AS3 void*)(dst + c * 8), 16, 0, 0);
  }
}

__device__ __forceinline__ bf16x8 frag_ld(const u16* s, int row, int colb) {
  return *reinterpret_cast<const bf16x8*>(
      reinterpret_cast<const char*>(s) + row * 128 + (colb ^ ((row & 7) << 4)));
}

// ---- flattened bijective XCD swizzle (total % 8 == 0 at all call sites) ----
#define XCD_DECODE2(TM, TN)                                                  \
  const int nxy = gridDim.x * gridDim.y;                                     \
  int flat = blockIdx.x + gridDim.x * blockIdx.y + nxy * blockIdx.z;         \
  const int total = nxy * gridDim.z;                                         \
  const int qq = total >> 3;                                                 \
  flat = (flat & 7) * qq + (flat >> 3);                                      \
  const int z = flat / nxy;                                                  \
  const int wg = flat % nxy;                                                 \
  const long m0 = (long)(wg % gridDim.x) * (TM);                             \
  const long n0 = (long)(wg / gridDim.x) * (TN);

// ============ 256x256 NT GEMM, BK=64, 8 waves, 4-phase, vmcnt(6)/phase ========
// R15 engine (session best): read-balance 0/4/8/12; ph3 pre-reads NEXT tile's
// A-lo + B-lo into persistent registers so ph0 has zero ds_reads.
#define BAR_PRE()       do { asm volatile("s_waitcnt vmcnt(6)" ::: "memory"); \
                             __builtin_amdgcn_s_barrier(); \
                             asm volatile("" ::: "memory"); } while (0)
#define BAR_POST()      do { asm volatile("" ::: "memory"); \
                             __builtin_amdgcn_s_barrier(); \
                             asm volatile("" ::: "memory"); } while (0)

template<bool OUT_F32>
__global__ __launch_bounds__(512, 2) void gemm_nt256(
    const u16* __restrict__ A, long lda, long sAz4, long sAz1,
    const u16* __restrict__ B, long ldb, long sBz4, long sBz1,
    void* __restrict__ Cv, long ldc, long sCz4, long sCz1,
    long cBatch, int cShift,
    int K, float scale)
{
  __shared__ u16 sm[2 * 32768] __attribute__((aligned(16)));  // 128 KiB

  const int t = threadIdx.x;
  XCD_DECODE2(256, 256);
  const long azoff = (long)(z >> 2) * sAz4 + (long)(z & 3) * sAz1;
  const long bzoff = (long)(z >> 2) * sBz4 + (long)(z & 3) * sBz1;
  const u16* Ab = A + azoff + m0 * lda;
  const u16* Bb = B + bzoff + n0 * ldb;

  const int wid = t >> 6, lane = t & 63;
  const int lhi = lane >> 4, llo = lane & 15;
  const int wm = wid >> 2, wn = wid & 3;

  f32x4 acc[2][4][2][2] = {};
  bf16x8 aLo[4][2], bl[2][2];    // persistent across iterations
  const int NT = K >> 6;

  stage_half(Ab, lda, 0, sm, t);
  stage_half(Bb + 128 * ldb, ldb, 0, sm + 16384 + 8192, t);
  stage_half(Bb, ldb, 0, sm + 16384, t);
  stage_half(Ab + 128 * lda, lda, 0, sm + 8192, t);
  stage_half(Ab, lda, 64, sm + 32768, t);
  stage_half(Bb + 128 * ldb, ldb, 64, sm + 32768 + 16384 + 8192, t);
  asm volatile("s_waitcnt vmcnt(4)" ::: "memory");
  __builtin_amdgcn_s_barrier();
  asm volatile("" ::: "memory");
  // pre-read tile0's A-lo + B-lo
#pragma unroll
  for (int fr = 0; fr < 4; ++fr)
#pragma unroll
    for (int kk = 0; kk < 2; ++kk)
      aLo[fr][kk] = frag_ld(sm, wm * 64 + fr * 16 + llo, (kk << 6) + (lhi << 4));
#pragma unroll
  for (int fc = 0; fc < 2; ++fc)
#pragma unroll
    for (int kk = 0; kk < 2; ++kk)
      bl[fc][kk] = frag_ld(sm + 16384, wn * 32 + fc * 16 + llo, (kk << 6) + (lhi << 4));

  for (int kt = 0; kt < NT; ++kt) {
    const int kb = kt & 1;
    u16* bc = sm + kb * 32768;
    u16* bn = sm + (kb ^ 1) * 32768;
    const u16* sAc = bc;
    const u16* sBc = bc + 16384;
    const int k1 = ((kt + 1 < NT) ? kt + 1 : 0) << 6;
    const int k2 = ((kt + 2 < NT) ? kt + 2 : kt + 2 - NT) << 6;

    bf16x8 aHi[4][2], bh[2][2];

    // ph0: stage B0(t+1); NO ds_reads; MFMA (Alo,Blo) from persistent regs
    stage_half(Bb, ldb, k1, bn + 16384, t);
    BAR_PRE();
    __builtin_amdgcn_s_setprio(1);
#pragma unroll
    for (int fr = 0; fr < 4; ++fr)
#pragma unroll
      for (int fc = 0; fc < 2; ++fc)
#pragma unroll
        for (int kk = 0; kk < 2; ++kk)
          acc[0][fr][0][fc] = __builtin_amdgcn_mfma_f32_16x16x32_bf16(aLo[fr][kk], bl[fc][kk], acc[0][fr][0][fc], 0, 0, 0);
    __builtin_amdgcn_s_setprio(0);
    BAR_POST();

    // ph1: read B-hi(4); stage A1(t+1); MFMA (Alo,Bhi)
#pragma unroll
    for (int fc = 0; fc < 2; ++fc)
#pragma unroll
      for (int kk = 0; kk < 2; ++kk)
        bh[fc][kk] = frag_ld(sBc, 128 + wn * 32 + fc * 16 + llo, (kk << 6) + (lhi << 4));
    stage_half(Ab + 128 * lda, lda, k1, bn + 8192, t);
    BAR_PRE();
    __builtin_amdgcn_s_setprio(1);
#pragma unroll
    for (int fr = 0; fr < 4; ++fr)
#pragma unroll
      for (int fc = 0; fc < 2; ++fc)
#pragma unroll
        for (int kk = 0; kk < 2; ++kk)
          acc[0][fr][1][fc] = __builtin_amdgcn_mfma_f32_16x16x32_bf16(aLo[fr][kk], bh[fc][kk], acc[0][fr][1][fc], 0, 0, 0);
    __builtin_amdgcn_s_setprio(0);
    BAR_POST();

    // ph2: read A-hi(8); stage A0(t+2); MFMA (Ahi,Bhi)
#pragma unroll
    for (int fr = 0; fr < 4; ++fr)
#pragma unroll
      for (int kk = 0; kk < 2; ++kk)
        aHi[fr][kk] = frag_ld(sAc, 128 + wm * 64 + fr * 16 + llo, (kk << 6) + (lhi << 4));
    stage_half(Ab, lda, k2, bc, t);
    BAR_PRE();
    __builtin_amdgcn_s_setprio(1);
#pragma unroll
    for (int fr = 0; fr < 4; ++fr)
#pragma unroll
      for (int fc = 0; fc < 2; ++fc)
#pragma unroll
        for (int kk = 0; kk < 2; ++kk)
          acc[1][fr][1][fc] = __builtin_amdgcn_mfma_f32_16x16x32_bf16(aHi[fr][kk], bh[fc][kk], acc[1][fr][1][fc], 0, 0, 0);
    __builtin_amdgcn_s_setprio(0);
    BAR_POST();

    // ph3: stage B1(t+2); BAR_PRE retires B0(t+1); MFMA (Ahi,Blo);
    //      then pre-read NEXT tile's A-lo + B-lo (latency spans 2 barriers)
    stage_half(Bb + 128 * ldb, ldb, k2, bc + 16384 + 8192, t);
    BAR_PRE();
    __builtin_amdgcn_s_setprio(1);
#pragma unroll
    for (int fr = 0; fr < 4; ++fr)
#pragma unroll
      for (int fc = 0; fc < 2; ++fc)
#pragma unroll
        for (int kk = 0; kk < 2; ++kk)
          acc[1][fr][0][fc] = __builtin_amdgcn_mfma_f32_16x16x32_bf16(aHi[fr][kk], bl[fc][kk], acc[1][fr][0][fc], 0, 0, 0);
    __builtin_amdgcn_s_setprio(0);
#pragma unroll
    for (int fr = 0; fr < 4; ++fr)
#pragma unroll
      for (int kk = 0; kk < 2; ++kk)
        aLo[fr][kk] = frag_ld(bn, wm * 64 + fr * 16 + llo, (kk << 6) + (lhi << 4));
#pragma unroll
    for (int fc = 0; fc < 2; ++fc)
#pragma unroll
      for (int kk = 0; kk < 2; ++kk)
        bl[fc][kk] = frag_ld(bn + 16384, wn * 32 + fc * 16 + llo, (kk << 6) + (lhi << 4));
    BAR_POST();
  }

  const long cb = n0 >> cShift;
  const long ncol0 = n0 - (cb << cShift);
  const long czoff = (long)(z >> 2) * sCz4 + (long)(z & 3) * sCz1 + cb * cBatch;
#pragma unroll
  for (int ah = 0; ah < 2; ++ah)
#pragma unroll
    for (int fr = 0; fr < 4; ++fr)
#pragma unroll
      for (int e = 0; e < 4; ++e) {
        const long r = m0 + ah * 128 + wm * 64 + fr * 16 + lhi * 4 + e;
#pragma unroll
        for (int bh2 = 0; bh2 < 2; ++bh2)
#pragma unroll
          for (int fc = 0; fc < 2; ++fc) {
            const long col = ncol0 + bh2 * 128 + wn * 32 + fc * 16 + llo;
            const float val = acc[ah][fr][bh2][fc][e] * scale;
            if (OUT_F32)
              ((float*)Cv)[czoff + r * ldc + col] = val;
            else
              ((u16*)Cv)[czoff + r * ldc + col] = f2bf(val);
          }
      }
}

// ===== 128x64 NT GEMM, BK=64, 4 waves (2x2), double-buffered (R14-proven) ====
template<bool OUT_F32>
__global__ __launch_bounds__(256, 3) void gemm_nt128x64(
    const u16* __restrict__ A, long lda, long sAz,
    const u16* __restrict__ B, long ldb, long sBz,
    void* __restrict__ Cv, long ldc, long sCz,
    int K, float scale)
{
  __shared__ u16 sm[2 * 12288] __attribute__((aligned(16)));  // 48 KiB

  const int t = threadIdx.x;
  XCD_DECODE2(128, 64);
  A += (long)z * sAz + m0 * lda;
  B += (long)z * sBz + n0 * ldb;

  const int wid = t >> 6, lane = t & 63;
  const int lhi = lane >> 4, llo = lane & 15;
  const int wr = (wid >> 1) * 64, wc = (wid & 1) * 32;

  f32x4 acc[4][2] = {};
  const int NT = K >> 6;   // >= 2

  stage_rows256<4>(A, lda, 0, sm, t);
  stage_rows256<2>(B, ldb, 0, sm + 8192, t);
  stage_rows256<4>(A, lda, 64, sm + 12288, t);
  stage_rows256<2>(B, ldb, 64, sm + 12288 + 8192, t);

  for (int kt = 0; kt < NT; ++kt) {
    asm volatile("s_waitcnt vmcnt(6)" ::: "memory");   // tile kt resident (own-wave)
    __builtin_amdgcn_s_barrier();
    asm volatile("" ::: "memory");
    u16* buf = sm + (kt & 1) * 12288;
    bf16x8 af[4][2], bfr[2][2];
#pragma unroll
    for (int i = 0; i < 4; ++i)
#pragma unroll
      for (int kk = 0; kk < 2; ++kk)
        af[i][kk] = frag_ld(buf, wr + i * 16 + llo, (kk << 6) + (lhi << 4));
#pragma unroll
    for (int j = 0; j < 2; ++j)
#pragma unroll
      for (int kk = 0; kk < 2; ++kk)
        bfr[j][kk] = frag_ld(buf + 8192, wc + j * 16 + llo, (kk << 6) + (lhi << 4));
    __builtin_amdgcn_s_setprio(1);
#pragma unroll
    for (int i = 0; i < 4; ++i)
#pragma unroll
      for (int j = 0; j < 2; ++j)
#pragma unroll
        for (int kk = 0; kk < 2; ++kk)
          acc[i][j] = __builtin_amdgcn_mfma_f32_16x16x32_bf16(af[i][kk], bfr[j][kk], acc[i][j], 0, 0, 0);
    __builtin_amdgcn_s_setprio(0);
    asm volatile("" ::: "memory");
    __builtin_amdgcn_s_barrier();
    asm volatile("" ::: "memory");
    const int k2 = ((kt + 2 < NT) ? kt + 2 : kt + 2 - NT) << 6;   // wrapped-dead at tail
    stage_rows256<4>(A, lda, k2, buf, t);
    stage_rows256<2>(B, ldb, k2, buf + 8192, t);
  }

#pragma unroll
  for (int i = 0; i < 4; ++i) {
#pragma unroll
    for (int e = 0; e < 4; ++e) {
      const long r = m0 + wr + i * 16 + lhi * 4 + e;
      if (OUT_F32) {
        float* C = (float*)Cv + (long)z * sCz + r * ldc + n0 + wc + llo;
#pragma unroll
        for (int j = 0; j < 2; ++j) C[j * 16] = acc[i][j][e] * scale;
      } else {
        u16* C = (u16*)Cv + (long)z * sCz + r * ldc + n0 + wc + llo;
#pragma unroll
        for (int j = 0; j < 2; ++j) C[j * 16] = f2bf(acc[i][j][e] * scale);
      }
    }
  }
}

// ---- reduce 4 split-K bf16 partials of G -> bf16 [4][1024][1024] ----
__global__ __launch_bounds__(256) void greduce4b(const u16* __restrict__ gp,
                                                 u16* __restrict__ gb) {
  const long o = (long)blockIdx.x * 256 + threadIdx.x;   // ushort8 index; 512K total
  const long b = o >> 17;
  const long r = o & 131071;
  float s[8] = {};
#pragma unroll
  for (int p = 0; p < 4; ++p) {
    ushort8 u = reinterpret_cast<const ushort8*>(gp)[((b * 4 + p) << 17) + r];
#pragma unroll
    for (int j = 0; j < 8; ++j) s[j] += bf2f(u[j]);
  }
  ushort8 out;
#pragma unroll
  for (int j = 0; j < 8; ++j) out[j] = f2bf(s[j]);
  reinterpret_cast<ushort8*>(gb)[o] = out;
}

// ---- single-pass row softmax on bf16 logits: att bf16 [4096][1024] -> P bf16 ----
__global__ __launch_bounds__(256) void softmax1b(const u16* __restrict__ att,
                                                 u16* __restrict__ P) {
  const long row = blockIdx.x;
  const int t = threadIdx.x;
  ushort4 u = reinterpret_cast<const ushort4*>(att + row * 1024)[t];
  const float v0 = bf2f(u.x), v1 = bf2f(u.y), v2 = bf2f(u.z), v3 = bf2f(u.w);
  float m = fmaxf(fmaxf(v0, v1), fmaxf(v2, v3));
#pragma unroll
  for (int off = 32; off > 0; off >>= 1) m = fmaxf(m, __shfl_down(m, off, 64));
  __shared__ float smax[4], ssum[4];
  const int wid = t >> 6, lane = t & 63;
  if (lane == 0) smax[wid] = m;
  __syncthreads();
  m = fmaxf(fmaxf(smax[0], smax[1]), fmaxf(smax[2], smax[3]));
  float e0 = expf(v0 - m), e1 = expf(v1 - m), e2 = expf(v2 - m), e3 = expf(v3 - m);
  float s = e0 + e1 + e2 + e3;
#pragma unroll
  for (int off = 32; off > 0; off >>= 1) s += __shfl_down(s, off, 64);
  if (lane == 0) ssum[wid] = s;
  __syncthreads();
  s = ssum[0] + ssum[1] + ssum[2] + ssum[3];
  float inv = 1.0f / s;
  ushort4 o;
  o.x = f2bf(e0 * inv); o.y = f2bf(e1 * inv); o.z = f2bf(e2 * inv); o.w = f2bf(e3 * inv);
  reinterpret_cast<ushort4*>(P + row * 1024)[t] = o;
}

extern "C" void kernel_launch(void* const* d_in, const int* in_sizes, int n_in,
                              void* d_out, int out_size, void* d_ws, size_t ws_size,
                              hipStream_t stream) {
  const float* x  = (const float*)d_in[0];
  const float* Wq = (const float*)d_in[1];
  const float* Wk = (const float*)d_in[2];
  const float* Wv = (const float*)d_in[3];
  const float* Wo = (const float*)d_in[4];

  const long M1 = 1L << 20;               // 1M elements

  // workspace layout (u16 elements)
  u16* xbf    = (u16*)d_ws;               // [16384][1024]                      16M
  u16* wq     = xbf + 16 * M1;            //                                     1M
  u16* wk     = wq + M1;                  //                                     1M
  u16* wv     = wk + M1;                  //                                     1M
  u16* wo     = wv + M1;                  //                                     1M
  u16* wvT    = wo + M1;                  // Wv^T                                1M
  u16* xT     = wvT + M1;                 // [4][1024 feat][4096 tok]           16M
  u16* gbf    = xT + 16 * M1;             // G bf16 [4][1024][1024]              4M
  u16* tbuf   = gbf + 4 * M1;             // T~ = Wq G                           4M
  u16* pbuf   = tbuf + 4 * M1;            // P (softmax)                         4M
  u16* rtb    = pbuf + 4 * M1;            // R^T                                 4M
  u16* sbuf   = rtb + 4 * M1;             // S = Wo R                            4M
  u16* gpartb = sbuf + 4 * M1;            // G bf16 partials [16][1024][1024]   16M
  u16* attb   = gpartb;                   // att bf16 [4][1024][1024] (aliases gpartb; disjoint lifetime)

  dim3 b256(256), b512(512);
  const long NOF = 0;
  const int NSH = 30;

  // conversions + transposes
  cvt_x_dual<<<dim3(16, 64, 4), b256, 0, stream>>>(x, xbf, xT);
  cvt_w4<<<dim3(4096), b256, 0, stream>>>(Wq, Wk, Wv, Wo, wq, wk, wv, wo);
  transpose_bf16<<<dim3(16, 16, 1), b256, 0, stream>>>(wv, 1024, 0, wvT, 1024, 0);

  // G[b] = x[b]^T x[b]  (M=N=1024, K=4096 split 4; z=b*4+p) -> bf16 partials
  gemm_nt256<false><<<dim3(4, 4, 16), b512, 0, stream>>>(
      xT, 4096, 1024L * 4096, 1024, xT, 4096, 1024L * 4096, 1024,
      (void*)gpartb, 1024, 4L << 20, 1L << 20, NOF, NSH, 1024, 1.0f);
  greduce4b<<<dim3(2048), b256, 0, stream>>>(gpartb, gbf);

  // T~[b] = Wq G[b]   (G symmetric -> NT form)
  gemm_nt128x64<false><<<dim3(8, 16, 4), b256, 0, stream>>>(
      wq, 1024, 0, gbf, 1024, M1, (void*)tbuf, 1024, M1, 1024, 1.0f);
  // att[b] = T~[b] Wk^T / 32 -> bf16 (gpartb dead after greduce4b)
  gemm_nt128x64<false><<<dim3(8, 16, 4), b256, 0, stream>>>(
      tbuf, 1024, M1, wk, 1024, 0, (void*)attb, 1024, M1, 1024, 1.0f / 32.0f);
  // softmax rows (bf16 logits) -> P bf16
  softmax1b<<<dim3(4096), b256, 0, stream>>>(attb, pbuf);

  // R^T[b]: C[e,k] = sum_j Wv[j,e] P[k,j]
  gemm_nt128x64<false><<<dim3(8, 16, 4), b256, 0, stream>>>(
      wvT, 1024, 0, pbuf, 1024, M1, (void*)rtb, 1024, M1, 1024, 1.0f);
  // S[b]: C[e',e] = sum_k Wo[e',k] RT[e,k]
  gemm_nt128x64<false><<<dim3(8, 16, 4), b256, 0, stream>>>(
      wo, 1024, 0, rtb, 1024, M1, (void*)sbuf, 1024, M1, 1024, 1.0f);

  // final[b] = x[b] S[b]^T  (M=4096/batch, N=1024, K=1024) -> d_out f32
  gemm_nt256<true><<<dim3(16, 4, 4), b512, 0, stream>>>(
      xbf, 1024, 0, 4096L * 1024, sbuf, 1024, 0, M1,
      d_out, 1024, 0, 4096L * 1024, NOF, NSH, 1024, 1.0f);
}

// Round 19
// 182.157 us; speedup vs baseline: 1.0464x; 1.0029x over previous
//
#include <hip/hip_runtime.h>
#include <hip/hip_bf16.h>

typedef unsigned short u16;
typedef __bf16 bf16x8 __attribute__((ext_vector_type(8)));
typedef float f32x4 __attribute__((ext_vector_type(4)));
typedef unsigned short ushort8 __attribute__((ext_vector_type(8)));

#define AS1 __attribute__((address_space(1)))
#define AS3 __attribute__((address_space(3)))

__device__ inline u16 f2bf(float f) {
  union { float f; unsigned int u; } c; c.f = f;
  unsigned int u = c.u;
  return (u16)((u + 0x7fffu + ((u >> 16) & 1u)) >> 16);
}
__device__ inline float bf2f(u16 v) {
  union { unsigned int u; float f; } c; c.u = ((unsigned int)v) << 16;
  return c.f;
}

// ---------------- fused x conversion + transpose ----------------
__global__ __launch_bounds__(256) void cvt_x_dual(const float* __restrict__ x,
                                                  u16* __restrict__ xbf,
                                                  u16* __restrict__ xT) {
  __shared__ u16 tile[64][68];
  const int t = threadIdx.x;
  const long e0 = (long)blockIdx.x * 64;     // feature tile
  const long l0 = (long)blockIdx.y * 64;     // token tile within batch
  const long b  = blockIdx.z;
  const int tr = t >> 4, tc = t & 15;
#pragma unroll
  for (int i = 0; i < 4; ++i) {
    const int r = tr + i * 16;
    const long gl = b * 4096 + l0 + r;
    float4 v = *reinterpret_cast<const float4*>(x + gl * 1024 + e0 + tc * 4);
    ushort4 o;
    o.x = f2bf(v.x); o.y = f2bf(v.y); o.z = f2bf(v.z); o.w = f2bf(v.w);
    *reinterpret_cast<ushort4*>(xbf + gl * 1024 + e0 + tc * 4) = o;
    *reinterpret_cast<ushort4*>(&tile[r][tc * 4]) = o;
  }
  __syncthreads();
#pragma unroll
  for (int i = 0; i < 4; ++i) {
    const int c = tr + i * 16;
    ushort4 o;
    o.x = tile[tc * 4 + 0][c]; o.y = tile[tc * 4 + 1][c];
    o.z = tile[tc * 4 + 2][c]; o.w = tile[tc * 4 + 3][c];
    *reinterpret_cast<ushort4*>(xT + b * (1024L * 4096) + (e0 + c) * 4096 + l0 + tc * 4) = o;
  }
}

// ---------------- fused conversion of 3 weight matrices (Wq, Wk, Wo) ----------
__global__ __launch_bounds__(256) void cvt_w3(const float* __restrict__ a, const float* __restrict__ b,
                                              const float* __restrict__ c,
                                              u16* __restrict__ oa, u16* __restrict__ ob,
                                              u16* __restrict__ oc) {
  int i = blockIdx.x * 256 + threadIdx.x;   // 3 * 262144 float4 chunks
  const int which = i >> 18;
  const int j = i & 262143;
  const float* src = which == 0 ? a : which == 1 ? b : c;
  u16* dst = which == 0 ? oa : which == 1 ? ob : oc;
  float4 v = reinterpret_cast<const float4*>(src)[j];
  ushort4 o;
  o.x = f2bf(v.x); o.y = f2bf(v.y); o.z = f2bf(v.z); o.w = f2bf(v.w);
  reinterpret_cast<ushort4*>(dst)[j] = o;
}

// ------- fused f32->bf16 transpose for Wv: wvT[c][r] = bf16(Wv[r][c]) --------
__global__ __launch_bounds__(256) void transpose_f32_wv(
    const float* __restrict__ src, u16* __restrict__ dst) {
  __shared__ u16 tile[64][68];
  const int t = threadIdx.x;
  const long r0 = (long)blockIdx.y * 64;
  const long c0 = (long)blockIdx.x * 64;
  const int tr = t >> 4, tc = t & 15;
#pragma unroll
  for (int i = 0; i < 4; ++i) {
    const int r = tr + i * 16;
    float4 v = *reinterpret_cast<const float4*>(src + (r0 + r) * 1024 + c0 + tc * 4);
    ushort4 o;
    o.x = f2bf(v.x); o.y = f2bf(v.y); o.z = f2bf(v.z); o.w = f2bf(v.w);
    *reinterpret_cast<ushort4*>(&tile[r][tc * 4]) = o;
  }
  __syncthreads();
#pragma unroll
  for (int i = 0; i < 4; ++i) {
    const int c = tr + i * 16;
    ushort4 o;
    o.x = tile[tc * 4 + 0][c]; o.y = tile[tc * 4 + 1][c];
    o.z = tile[tc * 4 + 2][c]; o.w = tile[tc * 4 + 3][c];
    *reinterpret_cast<ushort4*>(dst + (c0 + c) * 1024 + r0 + tc * 4) = o;
  }
}

// ---- staging helpers via gload_lds (pre-swizzled source) ----
__device__ __forceinline__ void stage_half(const u16* __restrict__ g, long ld, int k0,
                                           u16* dst, int t) {
#pragma unroll
  for (int i = 0; i < 2; ++i) {
    const int c = i * 512 + t;
    const int r = c >> 3;
    const int s = c & 7;
    const int col = ((s ^ (r & 7)) << 3) + k0;
    __builtin_amdgcn_global_load_lds((const AS1 void*)(g + (long)r * ld + col),
                                     (AS3 void*)(dst + c * 8), 16, 0, 0);
  }
}

// 256-thread variant: N16 chunks per thread (rows = N16*256/8)
template<int N16>
__device__ __forceinline__ void stage_rows256(const u16* __restrict__ g, long ld, int k0,
                                              u16* dst, int t) {
#pragma unroll
  for (int i = 0; i < N16; ++i) {
    const int c = i * 256 + t;
    const int r = c >> 3;
    const int s = c & 7;
    const int col = ((s ^ (r & 7)) << 3) + k0;
    __builtin_amdgcn_global_load_lds((const AS1 void*)(g + (long)r * ld + col),
                                     (AS3 void*)(dst + c * 8), 16, 0, 0);
  }
}

__device__ __forceinline__ bf16x8 frag_ld(const u16* s, int row, int colb) {
  return *reinterpret_cast<const bf16x8*>(
      reinterpret_cast<const char*>(s) + row * 128 + (colb ^ ((row & 7) << 4)));
}

// ---- flattened bijective XCD swizzle (total % 8 == 0 at all call sites) ----
#define XCD_DECODE2(TM, TN)                                                  \
  const int nxy = gridDim.x * gridDim.y;                                     \
  int flat = blockIdx.x + gridDim.x * blockIdx.y + nxy * blockIdx.z;         \
  const int total = nxy * gridDim.z;                                         \
  const int qq = total >> 3;                                                 \
  flat = (flat & 7) * qq + (flat >> 3);                                      \
  const int z = flat / nxy;                                                  \
  const int wg = flat % nxy;                                                 \
  const long m0 = (long)(wg % gridDim.x) * (TM);                             \
  const long n0 = (long)(wg / gridDim.x) * (TN);

// ============ 256x256 NT GEMM, BK=64, 8 waves, 4-phase, vmcnt(6)/phase ========
// R15 engine (session best): read-balance 0/4/8/12; ph3 pre-reads NEXT tile's
// A-lo + B-lo into persistent registers so ph0 has zero ds_reads.
#define BAR_PRE()       do { asm volatile("s_waitcnt vmcnt(6)" ::: "memory"); \
                             __builtin_amdgcn_s_barrier(); \
                             asm volatile("" ::: "memory"); } while (0)
#define BAR_POST()      do { asm volatile("" ::: "memory"); \
                             __builtin_amdgcn_s_barrier(); \
                             asm volatile("" ::: "memory"); } while (0)

template<bool OUT_F32>
__global__ __launch_bounds__(512, 2) void gemm_nt256(
    const u16* __restrict__ A, long lda, long sAz4, long sAz1,
    const u16* __restrict__ B, long ldb, long sBz4, long sBz1,
    void* __restrict__ Cv, long ldc, long sCz4, long sCz1,
    long cBatch, int cShift,
    int K, float scale)
{
  __shared__ u16 sm[2 * 32768] __attribute__((aligned(16)));  // 128 KiB

  const int t = threadIdx.x;
  XCD_DECODE2(256, 256);
  const long azoff = (long)(z >> 2) * sAz4 + (long)(z & 3) * sAz1;
  const long bzoff = (long)(z >> 2) * sBz4 + (long)(z & 3) * sBz1;
  const u16* Ab = A + azoff + m0 * lda;
  const u16* Bb = B + bzoff + n0 * ldb;

  const int wid = t >> 6, lane = t & 63;
  const int lhi = lane >> 4, llo = lane & 15;
  const int wm = wid >> 2, wn = wid & 3;

  f32x4 acc[2][4][2][2] = {};
  bf16x8 aLo[4][2], bl[2][2];    // persistent across iterations
  const int NT = K >> 6;

  stage_half(Ab, lda, 0, sm, t);
  stage_half(Bb + 128 * ldb, ldb, 0, sm + 16384 + 8192, t);
  stage_half(Bb, ldb, 0, sm + 16384, t);
  stage_half(Ab + 128 * lda, lda, 0, sm + 8192, t);
  stage_half(Ab, lda, 64, sm + 32768, t);
  stage_half(Bb + 128 * ldb, ldb, 64, sm + 32768 + 16384 + 8192, t);
  asm volatile("s_waitcnt vmcnt(4)" ::: "memory");
  __builtin_amdgcn_s_barrier();
  asm volatile("" ::: "memory");
  // pre-read tile0's A-lo + B-lo
#pragma unroll
  for (int fr = 0; fr < 4; ++fr)
#pragma unroll
    for (int kk = 0; kk < 2; ++kk)
      aLo[fr][kk] = frag_ld(sm, wm * 64 + fr * 16 + llo, (kk << 6) + (lhi << 4));
#pragma unroll
  for (int fc = 0; fc < 2; ++fc)
#pragma unroll
    for (int kk = 0; kk < 2; ++kk)
      bl[fc][kk] = frag_ld(sm + 16384, wn * 32 + fc * 16 + llo, (kk << 6) + (lhi << 4));

  for (int kt = 0; kt < NT; ++kt) {
    const int kb = kt & 1;
    u16* bc = sm + kb * 32768;
    u16* bn = sm + (kb ^ 1) * 32768;
    const u16* sAc = bc;
    const u16* sBc = bc + 16384;
    const int k1 = ((kt + 1 < NT) ? kt + 1 : 0) << 6;
    const int k2 = ((kt + 2 < NT) ? kt + 2 : kt + 2 - NT) << 6;

    bf16x8 aHi[4][2], bh[2][2];

    // ph0: stage B0(t+1); NO ds_reads; MFMA (Alo,Blo) from persistent regs
    stage_half(Bb, ldb, k1, bn + 16384, t);
    BAR_PRE();
    __builtin_amdgcn_s_setprio(1);
#pragma unroll
    for (int fr = 0; fr < 4; ++fr)
#pragma unroll
      for (int fc = 0; fc < 2; ++fc)
#pragma unroll
        for (int kk = 0; kk < 2; ++kk)
          acc[0][fr][0][fc] = __builtin_amdgcn_mfma_f32_16x16x32_bf16(aLo[fr][kk], bl[fc][kk], acc[0][fr][0][fc], 0, 0, 0);
    __builtin_amdgcn_s_setprio(0);
    BAR_POST();

    // ph1: read B-hi(4); stage A1(t+1); MFMA (Alo,Bhi)
#pragma unroll
    for (int fc = 0; fc < 2; ++fc)
#pragma unroll
      for (int kk = 0; kk < 2; ++kk)
        bh[fc][kk] = frag_ld(sBc, 128 + wn * 32 + fc * 16 + llo, (kk << 6) + (lhi << 4));
    stage_half(Ab + 128 * lda, lda, k1, bn + 8192, t);
    BAR_PRE();
    __builtin_amdgcn_s_setprio(1);
#pragma unroll
    for (int fr = 0; fr < 4; ++fr)
#pragma unroll
      for (int fc = 0; fc < 2; ++fc)
#pragma unroll
        for (int kk = 0; kk < 2; ++kk)
          acc[0][fr][1][fc] = __builtin_amdgcn_mfma_f32_16x16x32_bf16(aLo[fr][kk], bh[fc][kk], acc[0][fr][1][fc], 0, 0, 0);
    __builtin_amdgcn_s_setprio(0);
    BAR_POST();

    // ph2: read A-hi(8); stage A0(t+2); MFMA (Ahi,Bhi)
#pragma unroll
    for (int fr = 0; fr < 4; ++fr)
#pragma unroll
      for (int kk = 0; kk < 2; ++kk)
        aHi[fr][kk] = frag_ld(sAc, 128 + wm * 64 + fr * 16 + llo, (kk << 6) + (lhi << 4));
    stage_half(Ab, lda, k2, bc, t);
    BAR_PRE();
    __builtin_amdgcn_s_setprio(1);
#pragma unroll
    for (int fr = 0; fr < 4; ++fr)
#pragma unroll
      for (int fc = 0; fc < 2; ++fc)
#pragma unroll
        for (int kk = 0; kk < 2; ++kk)
          acc[1][fr][1][fc] = __builtin_amdgcn_mfma_f32_16x16x32_bf16(aHi[fr][kk], bh[fc][kk], acc[1][fr][1][fc], 0, 0, 0);
    __builtin_amdgcn_s_setprio(0);
    BAR_POST();

    // ph3: stage B1(t+2); BAR_PRE retires B0(t+1); MFMA (Ahi,Blo);
    //      then pre-read NEXT tile's A-lo + B-lo (latency spans 2 barriers)
    stage_half(Bb + 128 * ldb, ldb, k2, bc + 16384 + 8192, t);
    BAR_PRE();
    __builtin_amdgcn_s_setprio(1);
#pragma unroll
    for (int fr = 0; fr < 4; ++fr)
#pragma unroll
      for (int fc = 0; fc < 2; ++fc)
#pragma unroll
        for (int kk = 0; kk < 2; ++kk)
          acc[1][fr][0][fc] = __builtin_amdgcn_mfma_f32_16x16x32_bf16(aHi[fr][kk], bl[fc][kk], acc[1][fr][0][fc], 0, 0, 0);
    __builtin_amdgcn_s_setprio(0);
#pragma unroll
    for (int fr = 0; fr < 4; ++fr)
#pragma unroll
      for (int kk = 0; kk < 2; ++kk)
        aLo[fr][kk] = frag_ld(bn, wm * 64 + fr * 16 + llo, (kk << 6) + (lhi << 4));
#pragma unroll
    for (int fc = 0; fc < 2; ++fc)
#pragma unroll
      for (int kk = 0; kk < 2; ++kk)
        bl[fc][kk] = frag_ld(bn + 16384, wn * 32 + fc * 16 + llo, (kk << 6) + (lhi << 4));
    BAR_POST();
  }

  const long cb = n0 >> cShift;
  const long ncol0 = n0 - (cb << cShift);
  const long czoff = (long)(z >> 2) * sCz4 + (long)(z & 3) * sCz1 + cb * cBatch;
#pragma unroll
  for (int ah = 0; ah < 2; ++ah)
#pragma unroll
    for (int fr = 0; fr < 4; ++fr)
#pragma unroll
      for (int e = 0; e < 4; ++e) {
        const long r = m0 + ah * 128 + wm * 64 + fr * 16 + lhi * 4 + e;
#pragma unroll
        for (int bh2 = 0; bh2 < 2; ++bh2)
#pragma unroll
          for (int fc = 0; fc < 2; ++fc) {
            const long col = ncol0 + bh2 * 128 + wn * 32 + fc * 16 + llo;
            const float val = acc[ah][fr][bh2][fc][e] * scale;
            if (OUT_F32)
              ((float*)Cv)[czoff + r * ldc + col] = val;
            else
              ((u16*)Cv)[czoff + r * ldc + col] = f2bf(val);
          }
      }
}

// ===== 128x64 NT GEMM, BK=64, 4 waves (2x2), double-buffered (R14-proven) ====
template<bool OUT_F32>
__global__ __launch_bounds__(256, 3) void gemm_nt128x64(
    const u16* __restrict__ A, long lda, long sAz,
    const u16* __restrict__ B, long ldb, long sBz,
    void* __restrict__ Cv, long ldc, long sCz,
    int K, float scale)
{
  __shared__ u16 sm[2 * 12288] __attribute__((aligned(16)));  // 48 KiB

  const int t = threadIdx.x;
  XCD_DECODE2(128, 64);
  A += (long)z * sAz + m0 * lda;
  B += (long)z * sBz + n0 * ldb;

  const int wid = t >> 6, lane = t & 63;
  const int lhi = lane >> 4, llo = lane & 15;
  const int wr = (wid >> 1) * 64, wc = (wid & 1) * 32;

  f32x4 acc[4][2] = {};
  const int NT = K >> 6;   // >= 2

  stage_rows256<4>(A, lda, 0, sm, t);
  stage_rows256<2>(B, ldb, 0, sm + 8192, t);
  stage_rows256<4>(A, lda, 64, sm + 12288, t);
  stage_rows256<2>(B, ldb, 64, sm + 12288 + 8192, t);

  for (int kt = 0; kt < NT; ++kt) {
    asm volatile("s_waitcnt vmcnt(6)" ::: "memory");   // tile kt resident (own-wave)
    __builtin_amdgcn_s_barrier();
    asm volatile("" ::: "memory");
    u16* buf = sm + (kt & 1) * 12288;
    bf16x8 af[4][2], bfr[2][2];
#pragma unroll
    for (int i = 0; i < 4; ++i)
#pragma unroll
      for (int kk = 0; kk < 2; ++kk)
        af[i][kk] = frag_ld(buf, wr + i * 16 + llo, (kk << 6) + (lhi << 4));
#pragma unroll
    for (int j = 0; j < 2; ++j)
#pragma unroll
      for (int kk = 0; kk < 2; ++kk)
        bfr[j][kk] = frag_ld(buf + 8192, wc + j * 16 + llo, (kk << 6) + (lhi << 4));
    __builtin_amdgcn_s_setprio(1);
#pragma unroll
    for (int i = 0; i < 4; ++i)
#pragma unroll
      for (int j = 0; j < 2; ++j)
#pragma unroll
        for (int kk = 0; kk < 2; ++kk)
          acc[i][j] = __builtin_amdgcn_mfma_f32_16x16x32_bf16(af[i][kk], bfr[j][kk], acc[i][j], 0, 0, 0);
    __builtin_amdgcn_s_setprio(0);
    asm volatile("" ::: "memory");
    __builtin_amdgcn_s_barrier();
    asm volatile("" ::: "memory");
    const int k2 = ((kt + 2 < NT) ? kt + 2 : kt + 2 - NT) << 6;   // wrapped-dead at tail
    stage_rows256<4>(A, lda, k2, buf, t);
    stage_rows256<2>(B, ldb, k2, buf + 8192, t);
  }

#pragma unroll
  for (int i = 0; i < 4; ++i) {
#pragma unroll
    for (int e = 0; e < 4; ++e) {
      const long r = m0 + wr + i * 16 + lhi * 4 + e;
      if (OUT_F32) {
        float* C = (float*)Cv + (long)z * sCz + r * ldc + n0 + wc + llo;
#pragma unroll
        for (int j = 0; j < 2; ++j) C[j * 16] = acc[i][j][e] * scale;
      } else {
        u16* C = (u16*)Cv + (long)z * sCz + r * ldc + n0 + wc + llo;
#pragma unroll
        for (int j = 0; j < 2; ++j) C[j * 16] = f2bf(acc[i][j][e] * scale);
      }
    }
  }
}

// ---- reduce 4 split-K bf16 partials of G -> bf16 [4][1024][1024] ----
__global__ __launch_bounds__(256) void greduce4b(const u16* __restrict__ gp,
                                                 u16* __restrict__ gb) {
  const long o = (long)blockIdx.x * 256 + threadIdx.x;   // ushort8 index; 512K total
  const long b = o >> 17;
  const long r = o & 131071;
  float s[8] = {};
#pragma unroll
  for (int p = 0; p < 4; ++p) {
    ushort8 u = reinterpret_cast<const ushort8*>(gp)[((b * 4 + p) << 17) + r];
#pragma unroll
    for (int j = 0; j < 8; ++j) s[j] += bf2f(u[j]);
  }
  ushort8 out;
#pragma unroll
  for (int j = 0; j < 8; ++j) out[j] = f2bf(s[j]);
  reinterpret_cast<ushort8*>(gb)[o] = out;
}

// ---- single-pass row softmax on bf16 logits: att bf16 [4096][1024] -> P bf16 ----
__global__ __launch_bounds__(256) void softmax1b(const u16* __restrict__ att,
                                                 u16* __restrict__ P) {
  const long row = blockIdx.x;
  const int t = threadIdx.x;
  ushort4 u = reinterpret_cast<const ushort4*>(att + row * 1024)[t];
  const float v0 = bf2f(u.x), v1 = bf2f(u.y), v2 = bf2f(u.z), v3 = bf2f(u.w);
  float m = fmaxf(fmaxf(v0, v1), fmaxf(v2, v3));
#pragma unroll
  for (int off = 32; off > 0; off >>= 1) m = fmaxf(m, __shfl_down(m, off, 64));
  __shared__ float smax[4], ssum[4];
  const int wid = t >> 6, lane = t & 63;
  if (lane == 0) smax[wid] = m;
  __syncthreads();
  m = fmaxf(fmaxf(smax[0], smax[1]), fmaxf(smax[2], smax[3]));
  float e0 = expf(v0 - m), e1 = expf(v1 - m), e2 = expf(v2 - m), e3 = expf(v3 - m);
  float s = e0 + e1 + e2 + e3;
#pragma unroll
  for (int off = 32; off > 0; off >>= 1) s += __shfl_down(s, off, 64);
  if (lane == 0) ssum[wid] = s;
  __syncthreads();
  s = ssum[0] + ssum[1] + ssum[2] + ssum[3];
  float inv = 1.0f / s;
  ushort4 o;
  o.x = f2bf(e0 * inv); o.y = f2bf(e1 * inv); o.z = f2bf(e2 * inv); o.w = f2bf(e3 * inv);
  reinterpret_cast<ushort4*>(P + row * 1024)[t] = o;
}

extern "C" void kernel_launch(void* const* d_in, const int* in_sizes, int n_in,
                              void* d_out, int out_size, void* d_ws, size_t ws_size,
                              hipStream_t stream) {
  const float* x  = (const float*)d_in[0];
  const float* Wq = (const float*)d_in[1];
  const float* Wk = (const float*)d_in[2];
  const float* Wv = (const float*)d_in[3];
  const float* Wo = (const float*)d_in[4];

  const long M1 = 1L << 20;               // 1M elements

  // workspace layout (u16 elements)
  u16* xbf    = (u16*)d_ws;               // [16384][1024]                      16M
  u16* wq     = xbf + 16 * M1;            //                                     1M
  u16* wk     = wq + M1;                  //                                     1M
  u16* wo     = wk + M1;                  //                                     1M
  u16* wvT    = wo + M1;                  // Wv^T (fused cvt+transpose)          1M
  u16* xT     = wvT + M1;                 // [4][1024 feat][4096 tok]           16M
  u16* gbf    = xT + 16 * M1;             // G bf16 [4][1024][1024]              4M
  u16* tbuf   = gbf + 4 * M1;             // T~ = Wq G                           4M
  u16* pbuf   = tbuf + 4 * M1;            // P (softmax)                         4M
  u16* rtb    = pbuf + 4 * M1;            // R^T                                 4M
  u16* sbuf   = rtb + 4 * M1;             // S = Wo R                            4M
  u16* gpartb = sbuf + 4 * M1;            // G bf16 partials [16][1024][1024]   16M
  u16* attb   = gpartb;                   // att bf16 (aliases gpartb; disjoint lifetime)

  dim3 b256(256), b512(512);
  const long NOF = 0;
  const int NSH = 30;

  // conversions + transposes
  cvt_x_dual<<<dim3(16, 64, 4), b256, 0, stream>>>(x, xbf, xT);
  cvt_w3<<<dim3(3072), b256, 0, stream>>>(Wq, Wk, Wo, wq, wk, wo);
  transpose_f32_wv<<<dim3(16, 16, 1), b256, 0, stream>>>(Wv, wvT);

  // G[b] = x[b]^T x[b]  (M=N=1024, K=4096 split 4; z=b*4+p) -> bf16 partials
  gemm_nt256<false><<<dim3(4, 4, 16), b512, 0, stream>>>(
      xT, 4096, 1024L * 4096, 1024, xT, 4096, 1024L * 4096, 1024,
      (void*)gpartb, 1024, 4L << 20, 1L << 20, NOF, NSH, 1024, 1.0f);
  greduce4b<<<dim3(2048), b256, 0, stream>>>(gpartb, gbf);

  // T~[b] = Wq G[b]   (G symmetric -> NT form)
  gemm_nt128x64<false><<<dim3(8, 16, 4), b256, 0, stream>>>(
      wq, 1024, 0, gbf, 1024, M1, (void*)tbuf, 1024, M1, 1024, 1.0f);
  // att[b] = T~[b] Wk^T / 32 -> bf16 (gpartb dead after greduce4b)
  gemm_nt128x64<false><<<dim3(8, 16, 4), b256, 0, stream>>>(
      tbuf, 1024, M1, wk, 1024, 0, (void*)attb, 1024, M1, 1024, 1.0f / 32.0f);
  // softmax rows (bf16 logits) -> P bf16
  softmax1b<<<dim3(4096), b256, 0, stream>>>(attb, pbuf);

  // R^T[b]: C[e,k] = sum_j Wv[j,e] P[k,j]
  gemm_nt128x64<false><<<dim3(8, 16, 4), b256, 0, stream>>>(
      wvT, 1024, 0, pbuf, 1024, M1, (void*)rtb, 1024, M1, 1024, 1.0f);
  // S[b]: C[e',e] = sum_k Wo[e',k] RT[e,k]
  gemm_nt128x64<false><<<dim3(8, 16, 4), b256, 0, stream>>>(
      wo, 1024, 0, rtb, 1024, M1, (void*)sbuf, 1024, M1, 1024, 1.0f);

  // final[b] = x[b] S[b]^T  (M=4096/batch, N=1024, K=1024) -> d_out f32
  gemm_nt256<true><<<dim3(16, 4, 4), b512, 0, stream>>>(
      xbf, 1024, 0, 4096L * 1024, sbuf, 1024, 0, M1,
      d_out, 1024, 0, 4096L * 1024, NOF, NSH, 1024, 1.0f);
}